// Round 2
// 416.597 us; speedup vs baseline: 1.0053x; 1.0053x over previous
//
#include <hip/hip_runtime.h>
#include <hip/hip_bf16.h>
#include <stdint.h>

// Problem constants
#define S 1024
#define DMODEL 768
#define NH 12
#define DK 64
#define BB 4
#define BH 48      // BB*NH
#define M4 4096    // BB*S

typedef __attribute__((ext_vector_type(8))) short bf16x8;
typedef __attribute__((ext_vector_type(4))) float f32x4;
typedef __attribute__((ext_vector_type(4))) _Float16 f16x4;
typedef __attribute__((ext_vector_type(8))) _Float16 f16x8;

static __device__ __forceinline__ unsigned short f2bf(float f) {
  unsigned int u = __float_as_uint(f);
  unsigned int r = u + 0x7FFFu + ((u >> 16) & 1u);   // RNE
  return (unsigned short)(r >> 16);
}
static __device__ __forceinline__ bf16x8 ldfrag(const unsigned short* p) {
  uint4 q = *reinterpret_cast<const uint4*>(p);
  return __builtin_bit_cast(bf16x8, q);
}
static __device__ __forceinline__ f16x8 ldfragh(const unsigned short* p) {
  uint4 q = *reinterpret_cast<const uint4*>(p);
  return __builtin_bit_cast(f16x8, q);
}
static __device__ __forceinline__ unsigned short h2u(_Float16 h) {
  return __builtin_bit_cast(unsigned short, h);
}
// packed f32x4 -> f16x4 via v_cvt_pkrtz (2 instrs instead of 4 cvt + packing)
static __device__ __forceinline__ f16x4 pack4(const float* p) {
  auto lo = __builtin_amdgcn_cvt_pkrtz(p[0], p[1]);   // __fp16 ext_vector(2)
  auto hi = __builtin_amdgcn_cvt_pkrtz(p[2], p[3]);
  uint2 u;
  u.x = __builtin_bit_cast(unsigned int, lo);
  u.y = __builtin_bit_cast(unsigned int, hi);
  return __builtin_bit_cast(f16x4, u);
}
// async global->LDS, 16B per lane; LDS dest = wave-uniform base + lane*16
static __device__ __forceinline__ void gl2lds16(const unsigned short* g, unsigned short* l) {
  __builtin_amdgcn_global_load_lds(
      (const __attribute__((address_space(1))) unsigned int*)g,
      (__attribute__((address_space(3))) unsigned int*)l, 16, 0, 0);
}

// ---------------- f32 -> bf16 elementwise convert (both pro tensors, one launch) ----------------
__global__ __launch_bounds__(256) void k_convert(const float* __restrict__ i0, const float* __restrict__ i1,
                                                 unsigned short* __restrict__ o0, unsigned short* __restrict__ o1,
                                                 int n4) {
  const float* in = blockIdx.y ? i1 : i0;
  unsigned short* out = blockIdx.y ? o1 : o0;
  int i = blockIdx.x * 256 + threadIdx.x;
  if (i < n4) {
    float4 v = reinterpret_cast<const float4*>(in)[i];
    ushort4 o;
    o.x = f2bf(v.x); o.y = f2bf(v.y); o.z = f2bf(v.z); o.w = f2bf(v.w);
    reinterpret_cast<ushort4*>(out)[i] = o;
  }
}

// ---------------- W [k][n] f32 -> Wt [n][k] bf16 (768x768) ----------------
__global__ __launch_bounds__(256) void k_transpose(const float* w0, const float* w1, const float* w2,
                                                   unsigned short* o0, unsigned short* o1, unsigned short* o2) {
  const float* in = blockIdx.z == 0 ? w0 : (blockIdx.z == 1 ? w1 : w2);
  unsigned short* out = blockIdx.z == 0 ? o0 : (blockIdx.z == 1 ? o1 : o2);
  __shared__ float tile[32][33];
  int n0 = blockIdx.x * 32, k0 = blockIdx.y * 32;
  int tid = threadIdx.x;
  int r = tid >> 3, c = (tid & 7) * 4;
  float4 v = *reinterpret_cast<const float4*>(in + (size_t)(k0 + r) * DMODEL + n0 + c);
  tile[r][c] = v.x; tile[r][c + 1] = v.y; tile[r][c + 2] = v.z; tile[r][c + 3] = v.w;
  __syncthreads();
  ushort4 o;
  o.x = f2bf(tile[c + 0][r]);
  o.y = f2bf(tile[c + 1][r]);
  o.z = f2bf(tile[c + 2][r]);
  o.w = f2bf(tile[c + 3][r]);
  *reinterpret_cast<ushort4*>(out + (size_t)(n0 + r) * DMODEL + k0 + c) = o;
}

// ---------------- mask pack v3: int4 loads + raw-ballot-halves format ----------------
// Format: mp2[bh][wi][t], wi = g*8 + k*2 + h encodes column s = g*256 + (h*32+l)*4 + k
// at bit l of the 32-bit word. Packed words ARE the ballot halves (zero bit-twiddling).
// Per wave: one 64-row x 256-col tile (64 KB) via 64 coalesced int4 loads.
__global__ __launch_bounds__(256) void k_pack(const int* __restrict__ mask,
                                              unsigned int* __restrict__ mp2) {
  int bh = blockIdx.y;
  int w = threadIdx.x >> 6, lane = threadIdx.x & 63;
  int tile = blockIdx.x * 4 + w;          // 0..63
  int rowg = tile >> 2, colg = tile & 3;  // 16 row-groups x 4 col-groups
  int t0 = rowg * 64;
  const int* mb = mask + (size_t)bh * S * S + colg * 256;
  unsigned long long b0 = 0, b1 = 0, b2 = 0, b3 = 0;
#pragma unroll 8
  for (int r = 0; r < 64; ++r) {
    int4 v = *reinterpret_cast<const int4*>(mb + (size_t)(t0 + r) * S + lane * 4);
    unsigned long long c0 = __ballot(v.x != 0);
    unsigned long long c1 = __ballot(v.y != 0);
    unsigned long long c2 = __ballot(v.z != 0);
    unsigned long long c3 = __ballot(v.w != 0);
    if (lane == r) { b0 = c0; b1 = c1; b2 = c2; b3 = c3; }
  }
  unsigned int* p2 = mp2 + (size_t)bh * 32 * S + (size_t)(colg * 8) * S + t0 + lane;
  p2[(size_t)0 * S] = (unsigned)b0;  p2[(size_t)1 * S] = (unsigned)(b0 >> 32);
  p2[(size_t)2 * S] = (unsigned)b1;  p2[(size_t)3 * S] = (unsigned)(b1 >> 32);
  p2[(size_t)4 * S] = (unsigned)b2;  p2[(size_t)5 * S] = (unsigned)(b2 >> 32);
  p2[(size_t)6 * S] = (unsigned)b3;  p2[(size_t)7 * S] = (unsigned)(b3 >> 32);
}

// ---------------- 128x128-tile bf16 GEMM, m97-style global_load_lds K-loop ----------------
// mode 0: writes Q/K [BH][S][DK] f16 AND transposed [BH][DK][S] f16.
// mode 1: writes f16 [4096][768] (pre-LayerNorm).
__global__ __launch_bounds__(256, 3) void k_gemm(
    int mode,
    const unsigned short* __restrict__ A0, const unsigned short* __restrict__ A1,
    const unsigned short* __restrict__ Bt0, const unsigned short* __restrict__ Bt1,
    unsigned short* __restrict__ oQ0, unsigned short* __restrict__ oQ1,
    unsigned short* __restrict__ oT0, unsigned short* __restrict__ oT1,
    unsigned short* __restrict__ oH0, unsigned short* __restrict__ oH1) {
  const unsigned short* A = blockIdx.z ? A1 : A0;
  const unsigned short* Bt = blockIdx.z ? Bt1 : Bt0;
  __shared__ __align__(16) unsigned short As[128 * 64];   // 16384 B, unpadded
  __shared__ __align__(16) unsigned short Bs[128 * 64];   // 16384 B
  int tid = threadIdx.x;
  int m0 = blockIdx.x * 128, n0 = blockIdx.y * 128;
  int w = tid >> 6, lane = tid & 63, lane15 = lane & 15, quad = lane >> 4;
  int row0 = (w >> 1) * 64, col0 = (w & 1) * 64;
  f32x4 acc[4][4] = {};

  const unsigned short* gA[4];
  const unsigned short* gB[4];
  unsigned short* lA[4];
  unsigned short* lB[4];
  {
    int lr = lane >> 3;
    int ch = lane & 7;
#pragma unroll
    for (int i = 0; i < 4; ++i) {
      int r = w * 32 + i * 8 + lr;
      int cs = ((ch ^ (r & 7)) * 8);
      gA[i] = A + (size_t)(m0 + r) * DMODEL + cs;
      gB[i] = Bt + (size_t)(n0 + r) * DMODEL + cs;
      lA[i] = &As[(w * 32 + i * 8) * 64];
      lB[i] = &Bs[(w * 32 + i * 8) * 64];
    }
  }
  int l7 = lane15 & 7;
#pragma unroll
  for (int i = 0; i < 4; ++i) { gl2lds16(gA[i], lA[i]); gl2lds16(gB[i], lB[i]); }

  for (int kc = 0; kc < 12; ++kc) {
    __syncthreads();
#pragma unroll
    for (int ks = 0; ks < 2; ++ks) {
      int co = (((ks * 4 + quad) ^ l7) * 8);
      bf16x8 a[4], b[4];
#pragma unroll
      for (int i = 0; i < 4; ++i) a[i] = ldfrag(&As[(row0 + i * 16 + lane15) * 64 + co]);
#pragma unroll
      for (int j = 0; j < 4; ++j) b[j] = ldfrag(&Bs[(col0 + j * 16 + lane15) * 64 + co]);
#pragma unroll
      for (int i = 0; i < 4; ++i)
#pragma unroll
        for (int j = 0; j < 4; ++j)
          acc[i][j] = __builtin_amdgcn_mfma_f32_16x16x32_bf16(a[i], b[j], acc[i][j], 0, 0, 0);
    }
    __syncthreads();
    if (kc < 11) {
      int ko = (kc + 1) * 64;
#pragma unroll
      for (int i = 0; i < 4; ++i) { gl2lds16(gA[i] + ko, lA[i]); gl2lds16(gB[i] + ko, lB[i]); }
    }
  }

  if (mode == 0) {
    unsigned short* out = blockIdx.z ? oQ1 : oQ0;
    unsigned short* outT = blockIdx.z ? oT1 : oT0;
    f16x4 iden;
#pragma unroll
    for (int i = 0; i < 4; ++i) iden[i] = (_Float16)((quad * 4 + i) == lane15 ? 1.0f : 0.0f);
    f32x4 zero4 = {};
#pragma unroll
    for (int i = 0; i < 4; ++i)
#pragma unroll
      for (int j = 0; j < 4; ++j) {
        f16x4 cf;
#pragma unroll
        for (int reg = 0; reg < 4; ++reg) cf[reg] = (_Float16)acc[i][j][reg];
        f32x4 tq = __builtin_amdgcn_mfma_f32_16x16x16f16(cf, iden, zero4, 0, 0, 0);
        {
          int m = m0 + row0 + i * 16 + lane15;
          int n = n0 + col0 + j * 16 + quad * 4;
          int b = m >> 10, s = m & 1023, h = n >> 6, d = n & 63;
          ushort4 o;
          o.x = h2u((_Float16)tq[0]); o.y = h2u((_Float16)tq[1]);
          o.z = h2u((_Float16)tq[2]); o.w = h2u((_Float16)tq[3]);
          *reinterpret_cast<ushort4*>(&out[(((size_t)(b * NH + h)) * S + s) * DK + d]) = o;
        }
        {
          int n = n0 + col0 + j * 16 + lane15;
          int m = m0 + row0 + i * 16 + quad * 4;
          int b = m >> 10, s = m & 1023, h = n >> 6, d = n & 63;
          ushort4 o;
          o.x = h2u((_Float16)acc[i][j][0]); o.y = h2u((_Float16)acc[i][j][1]);
          o.z = h2u((_Float16)acc[i][j][2]); o.w = h2u((_Float16)acc[i][j][3]);
          *reinterpret_cast<ushort4*>(&outT[(((size_t)(b * NH + h)) * DK + d) * S + s]) = o;
        }
      }
  } else {
    unsigned short* outh = blockIdx.z ? oH1 : oH0;
#pragma unroll
    for (int i = 0; i < 4; ++i)
#pragma unroll
      for (int j = 0; j < 4; ++j)
#pragma unroll
        for (int reg = 0; reg < 4; ++reg) {
          int m = m0 + row0 + i * 16 + quad * 4 + reg;
          int n = n0 + col0 + j * 16 + lane15;
          outh[(size_t)m * DMODEL + n] = h2u((_Float16)acc[i][j][reg]);
        }
  }
}

// ---------------- fused dual-path attention ----------------
// (a) XCD-bijective block remap, (b) double-buffered LDS -> 1 barrier/chunk,
// (c) ballot-half mask format (matches k_pack v3), (d) cvt_pkrtz packed P->f16.
__global__ __launch_bounds__(256, 3) void k_attn(
    const unsigned short* __restrict__ Qb, const unsigned short* __restrict__ Kb,
    const unsigned short* __restrict__ QT, const unsigned short* __restrict__ KT,
    const unsigned int* __restrict__ mp2,
    unsigned short* __restrict__ c1, unsigned short* __restrict__ c2) {
  // XCD-grouped remap (bijective, 768 = 8 XCD * 96)
  int lin = blockIdx.x;
  int xcd = lin & 7, idx = lin >> 3;      // idx 0..95
  int grp = xcd * 12 + (idx >> 3);        // 0..95: (bh,path) group
  int sb = idx & 7;                       // s-block within group
  int path = grp >= 48 ? 1 : 0;
  int bh = grp - path * 48;
  int s0b = sb * 128;

  const unsigned short* X = path ? Kb : Qb;
  const unsigned short* Y = path ? Qb : Kb;
  const unsigned short* YT = path ? QT : KT;
  unsigned short* outc = path ? c2 : c1;

  __shared__ __align__(16) unsigned short YS[2][64 * 72];
  __shared__ __align__(16) unsigned short YTS[2][64 * 72];
  __shared__ __align__(16) unsigned int MWS[2][512];

  const unsigned short* Xb = X + (size_t)bh * S * DK;
  const unsigned short* Yb = Y + (size_t)bh * S * DK;
  const unsigned short* YTb = YT + (size_t)bh * DK * S;
  const unsigned int* mbg = mp2 + (size_t)bh * 32 * S;

  int tid = threadIdx.x;
  int w = tid >> 6, lane = tid & 63, lane15 = lane & 15, quad = lane >> 4;
  int s0w = s0b + w * 32;
  int ck = lane15 & 3;                 // path0 consumer word-select
  int sh0 = w * 8 + (lane15 >> 2);     // path0 consumer shift (rg=0); rg=1 -> +4

  // X fragments (MFMA B-operands for swapped QK)
  f16x8 xf[2][2];
#pragma unroll
  for (int rg = 0; rg < 2; ++rg) {
    xf[rg][0] = ldfragh(Xb + (size_t)(s0w + rg * 16 + lane15) * DK + quad * 8);
    xf[rg][1] = ldfragh(Xb + (size_t)(s0w + rg * 16 + lane15) * DK + 32 + quad * 8);
  }

  // Y/YT staging: thread covers row sr4 (0..63), 16 cols at sc4
  int sr4 = tid >> 2, sc4 = (tid & 3) * 16;
  const unsigned short* gY = Yb + (size_t)sr4 * DK + sc4;
  const unsigned short* gYT = YTb + (size_t)sr4 * S + sc4;
  uint4 y0 = *reinterpret_cast<const uint4*>(gY);
  uint4 y1 = *reinterpret_cast<const uint4*>(gY + 8);
  uint4 t0 = *reinterpret_cast<const uint4*>(gYT);
  uint4 t1 = *reinterpret_cast<const uint4*>(gYT + 8);

  // mask word prefetch (chunk 0)
  int mj = tid >> 2;                   // path0: j-row
  int p0wi = (sb >> 1) * 8 + (tid & 3) * 2 + (sb & 1);   // path0 staging word index
  int tl = tid >> 1;                   // path1: local t
  int k0 = (tid & 1) * 2, k1 = k0 + 1; // path1 staging k's
  unsigned mwv0, mwv1 = 0;
  if (path == 0) {
    mwv0 = mbg[(size_t)p0wi * S + mj];
  } else {
    mwv0 = mbg[(size_t)(k0 * 2) * S + s0b + tl];   // jcn=0 -> wbase=0
    mwv1 = mbg[(size_t)(k1 * 2) * S + s0b + tl];
  }

  f32x4 outa[2][4] = {};
  float lsum[2] = {0.f, 0.f};

  for (int jc = 0; jc < 16; ++jc) {
    int buf = jc & 1;
    // stage chunk jc (regs -> LDS[buf]); safe: concurrent compute is jc-1 on buf^1
    *reinterpret_cast<uint4*>(&YS[buf][sr4 * 72 + sc4]) = y0;
    *reinterpret_cast<uint4*>(&YS[buf][sr4 * 72 + sc4 + 8]) = y1;
    *reinterpret_cast<uint4*>(&YTS[buf][sr4 * 72 + sc4]) = t0;
    *reinterpret_cast<uint4*>(&YTS[buf][sr4 * 72 + sc4 + 8]) = t1;
    if (path == 0) {
      MWS[buf][tid] = mwv0;            // idx = j*4 + k = tid
    } else {
      uint2 mw; mw.x = mwv0; mw.y = mwv1;
      *reinterpret_cast<uint2*>(&MWS[buf][tid * 2]) = mw;   // (tl, k0),(tl, k1)
    }
    // prefetch chunk jc+1 (clamped)
    {
      int jcn = (jc + 1 < 16) ? jc + 1 : jc;
      int jn = jcn * 64;
      y0 = *reinterpret_cast<const uint4*>(gY + (size_t)jn * DK);
      y1 = *reinterpret_cast<const uint4*>(gY + (size_t)jn * DK + 8);
      t0 = *reinterpret_cast<const uint4*>(gYT + jn);
      t1 = *reinterpret_cast<const uint4*>(gYT + jn + 8);
      if (path == 0) {
        mwv0 = mbg[(size_t)p0wi * S + jn + mj];
      } else {
        size_t wb = (size_t)((jcn >> 2) * 8 + ((jcn >> 1) & 1)) * S + s0b + tl;
        mwv0 = mbg[wb + (size_t)(k0 * 2) * S];
        mwv1 = mbg[wb + (size_t)(k1 * 2) * S];
      }
    }
    __syncthreads();   // chunk jc resident for all waves

    // swapped QK: S^T[j][s] frags, C(row=j=quad*4+reg, col=s=lane15)
    f32x4 scv[4][2];
#pragma unroll
    for (int st = 0; st < 4; ++st) {
      f16x8 a0 = ldfragh(&YS[buf][(st * 16 + lane15) * 72 + quad * 8]);
      f16x8 a1 = ldfragh(&YS[buf][(st * 16 + lane15) * 72 + 32 + quad * 8]);
#pragma unroll
      for (int rg = 0; rg < 2; ++rg) {
        f32x4 v = {};
        v = __builtin_amdgcn_mfma_f32_16x16x32_f16(a0, xf[rg][0], v, 0, 0, 0);
        v = __builtin_amdgcn_mfma_f32_16x16x32_f16(a1, xf[rg][1], v, 0, 0, 0);
        scv[st][rg] = v;
      }
    }
    // mask + exp; P^T frags feed PV directly
    f16x4 pfa[4][2];
    if (path == 0) {
#pragma unroll
      for (int st = 0; st < 4; ++st) {
        float pv[2][4];
#pragma unroll
        for (int reg = 0; reg < 4; ++reg) {
          unsigned wdv = MWS[buf][(st * 16 + quad * 4 + reg) * 4 + ck];
#pragma unroll
          for (int rg = 0; rg < 2; ++rg) {
            float e = __expf(scv[st][rg][reg] * 0.125f);
            float p = ((wdv >> (unsigned)(sh0 + rg * 4)) & 1u) ? 0.f : e;
            lsum[rg] += p;
            pv[rg][reg] = p;
          }
        }
        pfa[st][0] = pack4(pv[0]);
        pfa[st][1] = pack4(pv[1]);
      }
    } else {
#pragma unroll
      for (int rg = 0; rg < 2; ++rg) {
        int bidx = (w * 32 + rg * 16 + lane15) * 4;
        uint4 wq = *reinterpret_cast<const uint4*>(&MWS[buf][bidx]);
        unsigned wd4[4] = {wq.x, wq.y, wq.z, wq.w};
#pragma unroll
        for (int st = 0; st < 4; ++st) {
          float pv[4];
          unsigned shb = (unsigned)((jc & 1) * 16 + st * 4 + quad);
#pragma unroll
          for (int reg = 0; reg < 4; ++reg) {
            float e = __expf(scv[st][rg][reg] * 0.125f);
            float p = ((wd4[reg] >> shb) & 1u) ? 0.f : e;
            lsum[rg] += p;
            pv[reg] = p;
          }
          pfa[st][rg] = pack4(pv);
        }
      }
    }
    // PV: outa[rg][dsub] += P^T_frag (A) x Y (B from YTS, b64 reads)
#pragma unroll
    for (int st = 0; st < 4; ++st)
#pragma unroll
      for (int dsub = 0; dsub < 4; ++dsub) {
        uint2 q = *reinterpret_cast<const uint2*>(&YTS[buf][(dsub * 16 + lane15) * 72 + st * 16 + quad * 4]);
        f16x4 yb = __builtin_bit_cast(f16x4, q);
#pragma unroll
        for (int rg = 0; rg < 2; ++rg)
          outa[rg][dsub] = __builtin_amdgcn_mfma_f32_16x16x16f16(pfa[st][rg], yb, outa[rg][dsub], 0, 0, 0);
      }
  }

  // row sums: reduce across quads
#pragma unroll
  for (int rg = 0; rg < 2; ++rg) {
    lsum[rg] += __shfl_xor(lsum[rg], 16);
    lsum[rg] += __shfl_xor(lsum[rg], 32);
  }
  float rinv[2][4];
#pragma unroll
  for (int rg = 0; rg < 2; ++rg)
#pragma unroll
    for (int reg = 0; reg < 4; ++reg)
      rinv[rg][reg] = 1.0f / __shfl(lsum[rg], quad * 4 + reg);

  int b = bh / NH, h = bh % NH;
#pragma unroll
  for (int rg = 0; rg < 2; ++rg)
#pragma unroll
    for (int dsub = 0; dsub < 4; ++dsub)
#pragma unroll
      for (int reg = 0; reg < 4; ++reg) {
        float v = outa[rg][dsub][reg] * rinv[rg][reg];
        int srow = s0w + rg * 16 + quad * 4 + reg;
        size_t idxo = ((size_t)(b * S) + srow) * DMODEL + h * DK + dsub * 16 + lane15;
        outc[idxo] = f2bf(v);
      }
}

// ---------------- LayerNorm over 768 (f16 input), one block per row ----------------
__global__ __launch_bounds__(256) void k_ln(const unsigned short* __restrict__ f1,
                                            const unsigned short* __restrict__ f2,
                                            const float* __restrict__ g1, const float* __restrict__ b1,
                                            const float* __restrict__ g2, const float* __restrict__ b2,
                                            float* __restrict__ out) {
  int rowg = blockIdx.x;
  int sel = rowg >> 12;
  int row = rowg & 4095;
  const unsigned short* in = sel ? f2 : f1;
  const float* g = sel ? g2 : g1;
  const float* be = sel ? b2 : b1;
  int tid = threadIdx.x;
  const unsigned short* p = in + (size_t)row * DMODEL;
  float x0 = (float)__builtin_bit_cast(_Float16, p[tid]);
  float x1 = (float)__builtin_bit_cast(_Float16, p[tid + 256]);
  float x2 = (float)__builtin_bit_cast(_Float16, p[tid + 512]);
  float s = x0 + x1 + x2;
  float ss = x0 * x0 + x1 * x1 + x2 * x2;
#pragma unroll
  for (int m = 1; m < 64; m <<= 1) { s += __shfl_xor(s, m); ss += __shfl_xor(ss, m); }
  __shared__ float ps[4], pss[4];
  int w = tid >> 6;
  if ((tid & 63) == 0) { ps[w] = s; pss[w] = ss; }
  __syncthreads();
  s = ps[0] + ps[1] + ps[2] + ps[3];
  ss = pss[0] + pss[1] + pss[2] + pss[3];
  float mu = s * (1.0f / 768.0f);
  float var = ss * (1.0f / 768.0f) - mu * mu;
  float rstd = rsqrtf(var + 1e-5f);
  float* o = out + ((size_t)sel * M4 + row) * DMODEL;
  o[tid] = (x0 - mu) * rstd * g[tid] + be[tid];
  o[tid + 256] = (x1 - mu) * rstd * g[tid + 256] + be[tid + 256];
  o[tid + 512] = (x2 - mu) * rstd * g[tid + 512] + be[tid + 512];
}

extern "C" void kernel_launch(void* const* d_in, const int* in_sizes, int n_in,
                              void* d_out, int out_size, void* d_ws, size_t ws_size,
                              hipStream_t stream) {
  const float* pro1 = (const float*)d_in[0];
  const float* pro2 = (const float*)d_in[1];
  const int* mask = (const int*)d_in[2];
  const float* WQ = (const float*)d_in[3];
  const float* WK = (const float*)d_in[4];
  const float* FC1 = (const float*)d_in[5];
  const float* g1 = (const float*)d_in[6];
  const float* b1 = (const float*)d_in[7];
  const float* g2 = (const float*)d_in[8];
  const float* b2 = (const float*)d_in[9];
  float* out = (float*)d_out;
  char* ws = (char*)d_ws;

  // workspace layout (bytes)
  unsigned short* pro1b = (unsigned short*)(ws + 0);          // 6291456 bf16
  unsigned short* pro2b = (unsigned short*)(ws + 6291456);    // 6291456 bf16
  unsigned short* f1h = (unsigned short*)(ws + 0);            // overlays pro1b (dead by gemm1)
  unsigned short* wqt = (unsigned short*)(ws + 12582912);     // 1179648
  unsigned short* wkt = (unsigned short*)(ws + 13762560);     // 1179648
  unsigned short* fc1t = (unsigned short*)(ws + 14942208);    // 1179648
  unsigned short* Qb = (unsigned short*)(ws + 16121856);      // 6291456 f16 [bh][s][d]
  unsigned short* Kb = (unsigned short*)(ws + 22413312);      // 6291456 f16
  unsigned short* QT = (unsigned short*)(ws + 28704768);      // 6291456 f16 [bh][d][s]
  unsigned short* KT = (unsigned short*)(ws + 34996224);      // 6291456 f16
  unsigned int* mp2 = (unsigned int*)(ws + 41287680);         // 6291456
  unsigned short* f2h = (unsigned short*)(ws + 47579136);     // 6291456 f16
  unsigned short* c1 = (unsigned short*)(ws + 60162048);      // 6291456 bf16
  unsigned short* c2 = (unsigned short*)(ws + 66453504);      // 6291456 bf16

  k_convert<<<dim3(3072, 2), 256, 0, stream>>>(pro1, pro2, pro1b, pro2b, 786432);
  k_transpose<<<dim3(24, 24, 3), 256, 0, stream>>>(WQ, WK, FC1, wqt, wkt, fc1t);
  k_pack<<<dim3(16, BH), 256, 0, stream>>>(mask, mp2);
  k_gemm<<<dim3(32, 6, 2), 256, 0, stream>>>(0, pro1b, pro2b, wqt, wkt,
                                             Qb, Kb, QT, KT, nullptr, nullptr);
  k_attn<<<dim3(768), 256, 0, stream>>>(Qb, Kb, QT, KT, mp2, c1, c2);
  k_gemm<<<dim3(32, 6, 2), 256, 0, stream>>>(1, c1, c2, fc1t, fc1t,
                                             nullptr, nullptr, nullptr, nullptr, f1h, f2h);
  k_ln<<<8192, 256, 0, stream>>>(f1h, f2h, g1, b1, g2, b2, out);
}

// Round 3
// 415.808 us; speedup vs baseline: 1.0072x; 1.0019x over previous
//
#include <hip/hip_runtime.h>
#include <hip/hip_bf16.h>
#include <stdint.h>

// Problem constants
#define S 1024
#define DMODEL 768
#define NH 12
#define DK 64
#define BB 4
#define BH 48      // BB*NH
#define M4 4096    // BB*S

typedef __attribute__((ext_vector_type(8))) short bf16x8;
typedef __attribute__((ext_vector_type(4))) float f32x4;
typedef __attribute__((ext_vector_type(4))) _Float16 f16x4;
typedef __attribute__((ext_vector_type(8))) _Float16 f16x8;

static __device__ __forceinline__ unsigned short f2bf(float f) {
  unsigned int u = __float_as_uint(f);
  unsigned int r = u + 0x7FFFu + ((u >> 16) & 1u);   // RNE
  return (unsigned short)(r >> 16);
}
// packed f32 pair -> bf16x2 dword (v_cvt_pk_bf16_f32, RNE); low16 = a
static __device__ __forceinline__ unsigned pkbf(float a, float b) {
  unsigned r;
  asm("v_cvt_pk_bf16_f32 %0, %1, %2" : "=v"(r) : "v"(a), "v"(b));
  return r;
}
static __device__ __forceinline__ bf16x8 ldfrag(const unsigned short* p) {
  uint4 q = *reinterpret_cast<const uint4*>(p);
  return __builtin_bit_cast(bf16x8, q);
}
static __device__ __forceinline__ f16x8 ldfragh(const unsigned short* p) {
  uint4 q = *reinterpret_cast<const uint4*>(p);
  return __builtin_bit_cast(f16x8, q);
}
static __device__ __forceinline__ unsigned short h2u(_Float16 h) {
  return __builtin_bit_cast(unsigned short, h);
}
// packed f32x4 -> f16x4 via v_cvt_pkrtz
static __device__ __forceinline__ f16x4 pack4(const float* p) {
  auto lo = __builtin_amdgcn_cvt_pkrtz(p[0], p[1]);   // __fp16 ext_vector(2)
  auto hi = __builtin_amdgcn_cvt_pkrtz(p[2], p[3]);
  uint2 u;
  u.x = __builtin_bit_cast(unsigned int, lo);
  u.y = __builtin_bit_cast(unsigned int, hi);
  return __builtin_bit_cast(f16x4, u);
}
// async global->LDS, 16B per lane; LDS dest = wave-uniform base + lane*16
static __device__ __forceinline__ void gl2lds16(const unsigned short* g, unsigned short* l) {
  __builtin_amdgcn_global_load_lds(
      (const __attribute__((address_space(1))) unsigned int*)g,
      (__attribute__((address_space(3))) unsigned int*)l, 16, 0, 0);
}

// ---------------- prep: W transpose (blocks 0..1727) + mask pack (blocks 1728..2495) ----------------
__global__ __launch_bounds__(256) void k_prep(const float* __restrict__ w0, const float* __restrict__ w1,
                                              const float* __restrict__ w2,
                                              unsigned short* __restrict__ o0, unsigned short* __restrict__ o1,
                                              unsigned short* __restrict__ o2,
                                              const int* __restrict__ mask, unsigned int* __restrict__ mp2) {
  int bid = blockIdx.x;
  int tid = threadIdx.x;
  if (bid < 1728) {
    // ---- 32x32 f32->bf16 transpose of one of 3 weight matrices ----
    int z = bid / 576;
    int r2 = bid - z * 576;
    int bx = r2 % 24, by = r2 / 24;
    const float* in = z == 0 ? w0 : (z == 1 ? w1 : w2);
    unsigned short* out = z == 0 ? o0 : (z == 1 ? o1 : o2);
    __shared__ float tile[32][33];
    int n0 = bx * 32, k0 = by * 32;
    int r = tid >> 3, c = (tid & 7) * 4;
    float4 v = *reinterpret_cast<const float4*>(in + (size_t)(k0 + r) * DMODEL + n0 + c);
    tile[r][c] = v.x; tile[r][c + 1] = v.y; tile[r][c + 2] = v.z; tile[r][c + 3] = v.w;
    __syncthreads();
    ushort4 o;
    o.x = f2bf(tile[c + 0][r]);
    o.y = f2bf(tile[c + 1][r]);
    o.z = f2bf(tile[c + 2][r]);
    o.w = f2bf(tile[c + 3][r]);
    *reinterpret_cast<ushort4*>(out + (size_t)(n0 + r) * DMODEL + k0 + c) = o;
  } else {
    // ---- mask pack: int4 loads + raw-ballot-halves format ----
    // mp2[bh][wi][t], wi = g*8 + k*2 + h holds bit l for column s = g*256 + (h*32+l)*4 + k
    int pb = bid - 1728;                    // 0..767
    int bh = pb >> 4;                       // 0..47
    int px = pb & 15;                       // 0..15
    int w = tid >> 6, lane = tid & 63;
    int tile4 = px * 4 + w;                 // 0..63
    int rowg = tile4 >> 2, colg = tile4 & 3;
    int t0 = rowg * 64;
    const int* mb = mask + (size_t)bh * S * S + colg * 256;
    unsigned long long b0 = 0, b1 = 0, b2 = 0, b3 = 0;
#pragma unroll 8
    for (int r = 0; r < 64; ++r) {
      int4 v = *reinterpret_cast<const int4*>(mb + (size_t)(t0 + r) * S + lane * 4);
      unsigned long long c0 = __ballot(v.x != 0);
      unsigned long long c1 = __ballot(v.y != 0);
      unsigned long long c2 = __ballot(v.z != 0);
      unsigned long long c3 = __ballot(v.w != 0);
      if (lane == r) { b0 = c0; b1 = c1; b2 = c2; b3 = c3; }
    }
    unsigned int* p2 = mp2 + (size_t)bh * 32 * S + (size_t)(colg * 8) * S + t0 + lane;
    p2[(size_t)0 * S] = (unsigned)b0;  p2[(size_t)1 * S] = (unsigned)(b0 >> 32);
    p2[(size_t)2 * S] = (unsigned)b1;  p2[(size_t)3 * S] = (unsigned)(b1 >> 32);
    p2[(size_t)4 * S] = (unsigned)b2;  p2[(size_t)5 * S] = (unsigned)(b2 >> 32);
    p2[(size_t)6 * S] = (unsigned)b3;  p2[(size_t)7 * S] = (unsigned)(b3 >> 32);
  }
}

// ---------------- 64x128-tile bf16 GEMM (3 blocks/CU uniform) ----------------
// mode 0: A = f32 (pro1/pro2), reg-staged + cvt_pk_bf16 -> LDS; writes Q/K [BH][S][DK]
//         f16 AND transposed [BH][DK][S] f16.
// mode 1: A = bf16 (c1/c2) via global_load_lds; writes f16 [4096][768].
// B always bf16 [n][k] via global_load_lds with global-side XOR chunk swizzle.
__global__ __launch_bounds__(256, 3) void k_gemm(
    int mode,
    const float* __restrict__ Af0, const float* __restrict__ Af1,
    const unsigned short* __restrict__ A0, const unsigned short* __restrict__ A1,
    const unsigned short* __restrict__ Bt0, const unsigned short* __restrict__ Bt1,
    unsigned short* __restrict__ oQ0, unsigned short* __restrict__ oQ1,
    unsigned short* __restrict__ oT0, unsigned short* __restrict__ oT1,
    unsigned short* __restrict__ oH0, unsigned short* __restrict__ oH1) {
  const unsigned short* Bt = blockIdx.z ? Bt1 : Bt0;
  __shared__ __align__(16) unsigned short As[64 * 64];    // 8192 B
  __shared__ __align__(16) unsigned short Bs[128 * 64];   // 16384 B
  int tid = threadIdx.x;
  int m0 = blockIdx.x * 64, n0 = blockIdx.y * 128;
  int w = tid >> 6, lane = tid & 63, lane15 = lane & 15, quad = lane >> 4;
  int col0 = w * 32;
  f32x4 acc[4][2] = {};

  // ---- B staging (both modes): wave w stages B rows [w*32, w*32+32), 4 gl2lds ----
  const unsigned short* gB[4];
  unsigned short* lB[4];
  // ---- A staging mode1: wave w stages A rows [w*16, w*16+16), 2 gl2lds ----
  const unsigned short* gA[2];
  unsigned short* lA[2];
  {
    int lr = lane >> 3, ch = lane & 7;
#pragma unroll
    for (int i = 0; i < 4; ++i) {
      int r = w * 32 + i * 8 + lr;
      int cs = ((ch ^ (r & 7)) * 8);
      gB[i] = Bt + (size_t)(n0 + r) * DMODEL + cs;
      lB[i] = &Bs[(w * 32 + i * 8) * 64];
    }
    if (mode != 0) {
      const unsigned short* A = blockIdx.z ? A1 : A0;
#pragma unroll
      for (int i = 0; i < 2; ++i) {
        int r = w * 16 + i * 8 + lr;
        int cs = ((ch ^ (r & 7)) * 8);
        gA[i] = A + (size_t)(m0 + r) * DMODEL + cs;
        lA[i] = &As[(w * 16 + i * 8) * 64];
      }
    }
  }
  // ---- A staging mode0: thread covers row ar (0..63), 16 f32 at col ac0 ----
  int ar = tid >> 2, aj0 = (tid & 3) * 2;          // source chunks aj0, aj0+1 (8 bf16 each)
  const float* gAf = nullptr;
  float4 af[4];
  if (mode == 0) {
    gAf = (blockIdx.z ? Af1 : Af0) + (size_t)(m0 + ar) * DMODEL + aj0 * 8;
#pragma unroll
    for (int q = 0; q < 4; ++q) af[q] = *reinterpret_cast<const float4*>(gAf + q * 4);
  }
  int arx = ar & 7;
  unsigned short* lAw0 = &As[ar * 64 + ((aj0 ^ arx) * 8)];
  unsigned short* lAw1 = &As[ar * 64 + (((aj0 + 1) ^ arx) * 8)];

  // prologue: stage tile 0
#pragma unroll
  for (int i = 0; i < 4; ++i) gl2lds16(gB[i], lB[i]);
  if (mode == 0) {
    uint4 w0, w1;
    w0.x = pkbf(af[0].x, af[0].y); w0.y = pkbf(af[0].z, af[0].w);
    w0.z = pkbf(af[1].x, af[1].y); w0.w = pkbf(af[1].z, af[1].w);
    w1.x = pkbf(af[2].x, af[2].y); w1.y = pkbf(af[2].z, af[2].w);
    w1.z = pkbf(af[3].x, af[3].y); w1.w = pkbf(af[3].z, af[3].w);
    *reinterpret_cast<uint4*>(lAw0) = w0;
    *reinterpret_cast<uint4*>(lAw1) = w1;
  } else {
#pragma unroll
    for (int i = 0; i < 2; ++i) gl2lds16(gA[i], lA[i]);
  }

  int l7 = lane15 & 7;
  for (int kc = 0; kc < 12; ++kc) {
    __syncthreads();   // tile kc resident + visible (drains vmcnt + lgkm)
    if (mode == 0 && kc < 11) {
      // issue next A f32 loads early; latency hides under MFMA
#pragma unroll
      for (int q = 0; q < 4; ++q)
        af[q] = *reinterpret_cast<const float4*>(gAf + (kc + 1) * 64 + q * 4);
    }
#pragma unroll
    for (int ks = 0; ks < 2; ++ks) {
      int co = (((ks * 4 + quad) ^ l7) * 8);
      bf16x8 a[4], b[2];
#pragma unroll
      for (int i = 0; i < 4; ++i) a[i] = ldfrag(&As[(i * 16 + lane15) * 64 + co]);
#pragma unroll
      for (int j = 0; j < 2; ++j) b[j] = ldfrag(&Bs[(col0 + j * 16 + lane15) * 64 + co]);
#pragma unroll
      for (int i = 0; i < 4; ++i)
#pragma unroll
        for (int j = 0; j < 2; ++j)
          acc[i][j] = __builtin_amdgcn_mfma_f32_16x16x32_bf16(a[i], b[j], acc[i][j], 0, 0, 0);
    }
    __syncthreads();   // all reads of tile kc done
    if (kc < 11) {
      int ko = (kc + 1) * 64;
#pragma unroll
      for (int i = 0; i < 4; ++i) gl2lds16(gB[i] + ko, lB[i]);
      if (mode == 0) {
        uint4 w0, w1;
        w0.x = pkbf(af[0].x, af[0].y); w0.y = pkbf(af[0].z, af[0].w);
        w0.z = pkbf(af[1].x, af[1].y); w0.w = pkbf(af[1].z, af[1].w);
        w1.x = pkbf(af[2].x, af[2].y); w1.y = pkbf(af[2].z, af[2].w);
        w1.z = pkbf(af[3].x, af[3].y); w1.w = pkbf(af[3].z, af[3].w);
        *reinterpret_cast<uint4*>(lAw0) = w0;
        *reinterpret_cast<uint4*>(lAw1) = w1;
      } else {
#pragma unroll
        for (int i = 0; i < 2; ++i) gl2lds16(gA[i] + ko, lA[i]);
      }
    }
  }

  if (mode == 0) {
    unsigned short* out = blockIdx.z ? oQ1 : oQ0;
    unsigned short* outT = blockIdx.z ? oT1 : oT0;
    f16x4 iden;
#pragma unroll
    for (int i = 0; i < 4; ++i) iden[i] = (_Float16)((quad * 4 + i) == lane15 ? 1.0f : 0.0f);
    f32x4 zero4 = {};
#pragma unroll
    for (int i = 0; i < 4; ++i)
#pragma unroll
      for (int j = 0; j < 2; ++j) {
        f16x4 cf;
#pragma unroll
        for (int reg = 0; reg < 4; ++reg) cf[reg] = (_Float16)acc[i][j][reg];
        f32x4 tq = __builtin_amdgcn_mfma_f32_16x16x16f16(cf, iden, zero4, 0, 0, 0);
        {   // Qb store: tq regs = 4 consecutive d, fixed s
          int m = m0 + i * 16 + lane15;
          int n = n0 + col0 + j * 16 + quad * 4;
          int b = m >> 10, s = m & 1023, h = n >> 6, d = n & 63;
          ushort4 o;
          o.x = h2u((_Float16)tq[0]); o.y = h2u((_Float16)tq[1]);
          o.z = h2u((_Float16)tq[2]); o.w = h2u((_Float16)tq[3]);
          *reinterpret_cast<ushort4*>(&out[(((size_t)(b * NH + h)) * S + s) * DK + d]) = o;
        }
        {   // QT store: acc regs = 4 consecutive s, fixed d
          int n = n0 + col0 + j * 16 + lane15;
          int m = m0 + i * 16 + quad * 4;
          int b = m >> 10, s = m & 1023, h = n >> 6, d = n & 63;
          ushort4 o;
          o.x = h2u((_Float16)acc[i][j][0]); o.y = h2u((_Float16)acc[i][j][1]);
          o.z = h2u((_Float16)acc[i][j][2]); o.w = h2u((_Float16)acc[i][j][3]);
          *reinterpret_cast<ushort4*>(&outT[(((size_t)(b * NH + h)) * DK + d) * S + s]) = o;
        }
      }
  } else {
    unsigned short* outh = blockIdx.z ? oH1 : oH0;
#pragma unroll
    for (int i = 0; i < 4; ++i)
#pragma unroll
      for (int j = 0; j < 2; ++j)
#pragma unroll
        for (int reg = 0; reg < 4; ++reg) {
          int m = m0 + i * 16 + quad * 4 + reg;
          int n = n0 + col0 + j * 16 + lane15;
          outh[(size_t)m * DMODEL + n] = h2u((_Float16)acc[i][j][reg]);
        }
  }
}

// ---------------- fused dual-path attention ----------------
// XCD-bijective remap, double-buffered LDS (1 barrier/chunk), ballot-half mask format,
// cvt_pkrtz packed P->f16, s_setprio around MFMA clusters.
__global__ __launch_bounds__(256, 3) void k_attn(
    const unsigned short* __restrict__ Qb, const unsigned short* __restrict__ Kb,
    const unsigned short* __restrict__ QT, const unsigned short* __restrict__ KT,
    const unsigned int* __restrict__ mp2,
    unsigned short* __restrict__ c1, unsigned short* __restrict__ c2) {
  // XCD-grouped remap (bijective, 768 = 8 XCD * 96)
  int lin = blockIdx.x;
  int xcd = lin & 7, idx = lin >> 3;      // idx 0..95
  int grp = xcd * 12 + (idx >> 3);        // 0..95: (bh,path) group
  int sb = idx & 7;                       // s-block within group
  int path = grp >= 48 ? 1 : 0;
  int bh = grp - path * 48;
  int s0b = sb * 128;

  const unsigned short* X = path ? Kb : Qb;
  const unsigned short* Y = path ? Qb : Kb;
  const unsigned short* YT = path ? QT : KT;
  unsigned short* outc = path ? c2 : c1;

  __shared__ __align__(16) unsigned short YS[2][64 * 72];
  __shared__ __align__(16) unsigned short YTS[2][64 * 72];
  __shared__ __align__(16) unsigned int MWS[2][512];

  const unsigned short* Xb = X + (size_t)bh * S * DK;
  const unsigned short* Yb = Y + (size_t)bh * S * DK;
  const unsigned short* YTb = YT + (size_t)bh * DK * S;
  const unsigned int* mbg = mp2 + (size_t)bh * 32 * S;

  int tid = threadIdx.x;
  int w = tid >> 6, lane = tid & 63, lane15 = lane & 15, quad = lane >> 4;
  int s0w = s0b + w * 32;
  int ck = lane15 & 3;                 // path0 consumer word-select
  int sh0 = w * 8 + (lane15 >> 2);     // path0 consumer shift (rg=0); rg=1 -> +4

  // X fragments (MFMA B-operands for swapped QK)
  f16x8 xf[2][2];
#pragma unroll
  for (int rg = 0; rg < 2; ++rg) {
    xf[rg][0] = ldfragh(Xb + (size_t)(s0w + rg * 16 + lane15) * DK + quad * 8);
    xf[rg][1] = ldfragh(Xb + (size_t)(s0w + rg * 16 + lane15) * DK + 32 + quad * 8);
  }

  // Y/YT staging: thread covers row sr4 (0..63), 16 cols at sc4
  int sr4 = tid >> 2, sc4 = (tid & 3) * 16;
  const unsigned short* gY = Yb + (size_t)sr4 * DK + sc4;
  const unsigned short* gYT = YTb + (size_t)sr4 * S + sc4;
  uint4 y0 = *reinterpret_cast<const uint4*>(gY);
  uint4 y1 = *reinterpret_cast<const uint4*>(gY + 8);
  uint4 t0 = *reinterpret_cast<const uint4*>(gYT);
  uint4 t1 = *reinterpret_cast<const uint4*>(gYT + 8);

  // mask word prefetch (chunk 0)
  int mj = tid >> 2;                   // path0: j-row
  int p0wi = (sb >> 1) * 8 + (tid & 3) * 2 + (sb & 1);   // path0 staging word index
  int tl = tid >> 1;                   // path1: local t
  int k0 = (tid & 1) * 2, k1 = k0 + 1; // path1 staging k's
  unsigned mwv0, mwv1 = 0;
  if (path == 0) {
    mwv0 = mbg[(size_t)p0wi * S + mj];
  } else {
    mwv0 = mbg[(size_t)(k0 * 2) * S + s0b + tl];   // jcn=0 -> wbase=0
    mwv1 = mbg[(size_t)(k1 * 2) * S + s0b + tl];
  }

  f32x4 outa[2][4] = {};
  float lsum[2] = {0.f, 0.f};

  for (int jc = 0; jc < 16; ++jc) {
    int buf = jc & 1;
    // stage chunk jc (regs -> LDS[buf]); safe: concurrent compute is jc-1 on buf^1
    *reinterpret_cast<uint4*>(&YS[buf][sr4 * 72 + sc4]) = y0;
    *reinterpret_cast<uint4*>(&YS[buf][sr4 * 72 + sc4 + 8]) = y1;
    *reinterpret_cast<uint4*>(&YTS[buf][sr4 * 72 + sc4]) = t0;
    *reinterpret_cast<uint4*>(&YTS[buf][sr4 * 72 + sc4 + 8]) = t1;
    if (path == 0) {
      MWS[buf][tid] = mwv0;            // idx = j*4 + k = tid
    } else {
      uint2 mw; mw.x = mwv0; mw.y = mwv1;
      *reinterpret_cast<uint2*>(&MWS[buf][tid * 2]) = mw;   // (tl, k0),(tl, k1)
    }
    // prefetch chunk jc+1 (clamped)
    {
      int jcn = (jc + 1 < 16) ? jc + 1 : jc;
      int jn = jcn * 64;
      y0 = *reinterpret_cast<const uint4*>(gY + (size_t)jn * DK);
      y1 = *reinterpret_cast<const uint4*>(gY + (size_t)jn * DK + 8);
      t0 = *reinterpret_cast<const uint4*>(gYT + jn);
      t1 = *reinterpret_cast<const uint4*>(gYT + jn + 8);
      if (path == 0) {
        mwv0 = mbg[(size_t)p0wi * S + jn + (tid >> 2)];
      } else {
        size_t wb = (size_t)((jcn >> 2) * 8 + ((jcn >> 1) & 1)) * S + s0b + tl;
        mwv0 = mbg[wb + (size_t)(k0 * 2) * S];
        mwv1 = mbg[wb + (size_t)(k1 * 2) * S];
      }
    }
    __syncthreads();   // chunk jc resident for all waves

    // swapped QK: S^T[j][s] frags, C(row=j=quad*4+reg, col=s=lane15)
    f32x4 scv[4][2];
    __builtin_amdgcn_s_setprio(1);
#pragma unroll
    for (int st = 0; st < 4; ++st) {
      f16x8 a0 = ldfragh(&YS[buf][(st * 16 + lane15) * 72 + quad * 8]);
      f16x8 a1 = ldfragh(&YS[buf][(st * 16 + lane15) * 72 + 32 + quad * 8]);
#pragma unroll
      for (int rg = 0; rg < 2; ++rg) {
        f32x4 v = {};
        v = __builtin_amdgcn_mfma_f32_16x16x32_f16(a0, xf[rg][0], v, 0, 0, 0);
        v = __builtin_amdgcn_mfma_f32_16x16x32_f16(a1, xf[rg][1], v, 0, 0, 0);
        scv[st][rg] = v;
      }
    }
    __builtin_amdgcn_s_setprio(0);
    // mask + exp; P^T frags feed PV directly
    f16x4 pfa[4][2];
    if (path == 0) {
#pragma unroll
      for (int st = 0; st < 4; ++st) {
        float pv[2][4];
#pragma unroll
        for (int reg = 0; reg < 4; ++reg) {
          unsigned wdv = MWS[buf][(st * 16 + quad * 4 + reg) * 4 + ck];
#pragma unroll
          for (int rg = 0; rg < 2; ++rg) {
            float e = __expf(scv[st][rg][reg] * 0.125f);
            float p = ((wdv >> (unsigned)(sh0 + rg * 4)) & 1u) ? 0.f : e;
            lsum[rg] += p;
            pv[rg][reg] = p;
          }
        }
        pfa[st][0] = pack4(pv[0]);
        pfa[st][1] = pack4(pv[1]);
      }
    } else {
#pragma unroll
      for (int rg = 0; rg < 2; ++rg) {
        int bidx = (w * 32 + rg * 16 + lane15) * 4;
        uint4 wq = *reinterpret_cast<const uint4*>(&MWS[buf][bidx]);
        unsigned wd4[4] = {wq.x, wq.y, wq.z, wq.w};
#pragma unroll
        for (int st = 0; st < 4; ++st) {
          float pv[4];
          unsigned shb = (unsigned)((jc & 1) * 16 + st * 4 + quad);
#pragma unroll
          for (int reg = 0; reg < 4; ++reg) {
            float e = __expf(scv[st][rg][reg] * 0.125f);
            float p = ((wd4[reg] >> shb) & 1u) ? 0.f : e;
            lsum[rg] += p;
            pv[reg] = p;
          }
          pfa[st][rg] = pack4(pv);
        }
      }
    }
    // PV: outa[rg][dsub] += P^T_frag (A) x Y (B from YTS, b64 reads)
    __builtin_amdgcn_s_setprio(1);
#pragma unroll
    for (int st = 0; st < 4; ++st)
#pragma unroll
      for (int dsub = 0; dsub < 4; ++dsub) {
        uint2 q = *reinterpret_cast<const uint2*>(&YTS[buf][(dsub * 16 + lane15) * 72 + st * 16 + quad * 4]);
        f16x4 yb = __builtin_bit_cast(f16x4, q);
#pragma unroll
        for (int rg = 0; rg < 2; ++rg)
          outa[rg][dsub] = __builtin_amdgcn_mfma_f32_16x16x16f16(pfa[st][rg], yb, outa[rg][dsub], 0, 0, 0);
      }
    __builtin_amdgcn_s_setprio(0);
  }

  // row sums: reduce across quads
#pragma unroll
  for (int rg = 0; rg < 2; ++rg) {
    lsum[rg] += __shfl_xor(lsum[rg], 16);
    lsum[rg] += __shfl_xor(lsum[rg], 32);
  }
  float rinv[2][4];
#pragma unroll
  for (int rg = 0; rg < 2; ++rg)
#pragma unroll
    for (int reg = 0; reg < 4; ++reg)
      rinv[rg][reg] = 1.0f / __shfl(lsum[rg], quad * 4 + reg);

  int b = bh / NH, h = bh % NH;
#pragma unroll
  for (int rg = 0; rg < 2; ++rg)
#pragma unroll
    for (int dsub = 0; dsub < 4; ++dsub)
#pragma unroll
      for (int reg = 0; reg < 4; ++reg) {
        float v = outa[rg][dsub][reg] * rinv[rg][reg];
        int srow = s0w + rg * 16 + quad * 4 + reg;
        size_t idxo = ((size_t)(b * S) + srow) * DMODEL + h * DK + dsub * 16 + lane15;
        outc[idxo] = f2bf(v);
      }
}

// ---------------- LayerNorm over 768 (f16 input), one block per row ----------------
__global__ __launch_bounds__(256) void k_ln(const unsigned short* __restrict__ f1,
                                            const unsigned short* __restrict__ f2,
                                            const float* __restrict__ g1, const float* __restrict__ b1,
                                            const float* __restrict__ g2, const float* __restrict__ b2,
                                            float* __restrict__ out) {
  int rowg = blockIdx.x;
  int sel = rowg >> 12;
  int row = rowg & 4095;
  const unsigned short* in = sel ? f2 : f1;
  const float* g = sel ? g2 : g1;
  const float* be = sel ? b2 : b1;
  int tid = threadIdx.x;
  const unsigned short* p = in + (size_t)row * DMODEL;
  float x0 = (float)__builtin_bit_cast(_Float16, p[tid]);
  float x1 = (float)__builtin_bit_cast(_Float16, p[tid + 256]);
  float x2 = (float)__builtin_bit_cast(_Float16, p[tid + 512]);
  float s = x0 + x1 + x2;
  float ss = x0 * x0 + x1 * x1 + x2 * x2;
#pragma unroll
  for (int m = 1; m < 64; m <<= 1) { s += __shfl_xor(s, m); ss += __shfl_xor(ss, m); }
  __shared__ float ps[4], pss[4];
  int w = tid >> 6;
  if ((tid & 63) == 0) { ps[w] = s; pss[w] = ss; }
  __syncthreads();
  s = ps[0] + ps[1] + ps[2] + ps[3];
  ss = pss[0] + pss[1] + pss[2] + pss[3];
  float mu = s * (1.0f / 768.0f);
  float var = ss * (1.0f / 768.0f) - mu * mu;
  float rstd = rsqrtf(var + 1e-5f);
  float* o = out + ((size_t)sel * M4 + row) * DMODEL;
  o[tid] = (x0 - mu) * rstd * g[tid] + be[tid];
  o[tid + 256] = (x1 - mu) * rstd * g[tid + 256] + be[tid + 256];
  o[tid + 512] = (x2 - mu) * rstd * g[tid + 512] + be[tid + 512];
}

extern "C" void kernel_launch(void* const* d_in, const int* in_sizes, int n_in,
                              void* d_out, int out_size, void* d_ws, size_t ws_size,
                              hipStream_t stream) {
  const float* pro1 = (const float*)d_in[0];
  const float* pro2 = (const float*)d_in[1];
  const int* mask = (const int*)d_in[2];
  const float* WQ = (const float*)d_in[3];
  const float* WK = (const float*)d_in[4];
  const float* FC1 = (const float*)d_in[5];
  const float* g1 = (const float*)d_in[6];
  const float* b1 = (const float*)d_in[7];
  const float* g2 = (const float*)d_in[8];
  const float* b2 = (const float*)d_in[9];
  float* out = (float*)d_out;
  char* ws = (char*)d_ws;

  // workspace layout (bytes)
  unsigned short* f1h = (unsigned short*)(ws + 0);            // 6291456 f16 (pre-LN path1)
  unsigned short* wqt = (unsigned short*)(ws + 12582912);     // 1179648
  unsigned short* wkt = (unsigned short*)(ws + 13762560);     // 1179648
  unsigned short* fc1t = (unsigned short*)(ws + 14942208);    // 1179648
  unsigned short* Qb = (unsigned short*)(ws + 16121856);      // 6291456 f16 [bh][s][d]
  unsigned short* Kb = (unsigned short*)(ws + 22413312);      // 6291456 f16
  unsigned short* QT = (unsigned short*)(ws + 28704768);      // 6291456 f16 [bh][d][s]
  unsigned short* KT = (unsigned short*)(ws + 34996224);      // 6291456 f16
  unsigned int* mp2 = (unsigned int*)(ws + 41287680);         // 6291456
  unsigned short* f2h = (unsigned short*)(ws + 47579136);     // 6291456 f16
  unsigned short* c1 = (unsigned short*)(ws + 60162048);      // 6291456 bf16
  unsigned short* c2 = (unsigned short*)(ws + 66453504);      // 6291456 bf16

  k_prep<<<2496, 256, 0, stream>>>(WQ, WK, FC1, wqt, wkt, fc1t, mask, mp2);
  k_gemm<<<dim3(64, 6, 2), 256, 0, stream>>>(0, pro1, pro2, nullptr, nullptr, wqt, wkt,
                                             Qb, Kb, QT, KT, nullptr, nullptr);
  k_attn<<<dim3(768), 256, 0, stream>>>(Qb, Kb, QT, KT, mp2, c1, c2);
  k_gemm<<<dim3(64, 6, 2), 256, 0, stream>>>(1, nullptr, nullptr, c1, c2, fc1t, fc1t,
                                             nullptr, nullptr, nullptr, nullptr, f1h, f2h);
  k_ln<<<8192, 256, 0, stream>>>(f1h, f2h, g1, b1, g2, b2, out);
}

// Round 4
// 407.657 us; speedup vs baseline: 1.0274x; 1.0200x over previous
//
#include <hip/hip_runtime.h>
#include <hip/hip_bf16.h>
#include <stdint.h>

// Problem constants
#define S 1024
#define DMODEL 768
#define NH 12
#define DK 64
#define BB 4
#define BH 48      // BB*NH
#define M4 4096    // BB*S

typedef __attribute__((ext_vector_type(8))) short bf16x8;
typedef __attribute__((ext_vector_type(4))) float f32x4;
typedef __attribute__((ext_vector_type(4))) _Float16 f16x4;
typedef __attribute__((ext_vector_type(8))) _Float16 f16x8;

static __device__ __forceinline__ unsigned short f2bf(float f) {
  unsigned int u = __float_as_uint(f);
  unsigned int r = u + 0x7FFFu + ((u >> 16) & 1u);   // RNE
  return (unsigned short)(r >> 16);
}
// packed f32 pair -> bf16x2 dword (v_cvt_pk_bf16_f32, RNE); low16 = a
static __device__ __forceinline__ unsigned pkbf(float a, float b) {
  unsigned r;
  asm("v_cvt_pk_bf16_f32 %0, %1, %2" : "=v"(r) : "v"(a), "v"(b));
  return r;
}
static __device__ __forceinline__ bf16x8 ldfrag(const unsigned short* p) {
  uint4 q = *reinterpret_cast<const uint4*>(p);
  return __builtin_bit_cast(bf16x8, q);
}
static __device__ __forceinline__ f16x8 ldfragh(const unsigned short* p) {
  uint4 q = *reinterpret_cast<const uint4*>(p);
  return __builtin_bit_cast(f16x8, q);
}
static __device__ __forceinline__ unsigned short h2u(_Float16 h) {
  return __builtin_bit_cast(unsigned short, h);
}
// packed f32x4 -> f16x4 via v_cvt_pkrtz
static __device__ __forceinline__ f16x4 pack4(const float* p) {
  auto lo = __builtin_amdgcn_cvt_pkrtz(p[0], p[1]);   // __fp16 ext_vector(2)
  auto hi = __builtin_amdgcn_cvt_pkrtz(p[2], p[3]);
  uint2 u;
  u.x = __builtin_bit_cast(unsigned int, lo);
  u.y = __builtin_bit_cast(unsigned int, hi);
  return __builtin_bit_cast(f16x4, u);
}
// async global->LDS, 16B per lane; LDS dest = wave-uniform base + lane*16
static __device__ __forceinline__ void gl2lds16(const unsigned short* g, unsigned short* l) {
  __builtin_amdgcn_global_load_lds(
      (const __attribute__((address_space(1))) unsigned int*)g,
      (__attribute__((address_space(3))) unsigned int*)l, 16, 0, 0);
}

// ---------------- prep: W [k][n] f32 -> Wt [n][k] bf16 (3x 768x768) ----------------
__global__ __launch_bounds__(256) void k_prep(const float* __restrict__ w0, const float* __restrict__ w1,
                                              const float* __restrict__ w2,
                                              unsigned short* __restrict__ o0, unsigned short* __restrict__ o1,
                                              unsigned short* __restrict__ o2) {
  int bid = blockIdx.x;
  int tid = threadIdx.x;
  int z = bid / 576;
  int r2 = bid - z * 576;
  int bx = r2 % 24, by = r2 / 24;
  const float* in = z == 0 ? w0 : (z == 1 ? w1 : w2);
  unsigned short* out = z == 0 ? o0 : (z == 1 ? o1 : o2);
  __shared__ float tile[32][33];
  int n0 = bx * 32, k0 = by * 32;
  int r = tid >> 3, c = (tid & 7) * 4;
  float4 v = *reinterpret_cast<const float4*>(in + (size_t)(k0 + r) * DMODEL + n0 + c);
  tile[r][c] = v.x; tile[r][c + 1] = v.y; tile[r][c + 2] = v.z; tile[r][c + 3] = v.w;
  __syncthreads();
  ushort4 o;
  o.x = f2bf(tile[c + 0][r]);
  o.y = f2bf(tile[c + 1][r]);
  o.z = f2bf(tile[c + 2][r]);
  o.w = f2bf(tile[c + 3][r]);
  *reinterpret_cast<ushort4*>(out + (size_t)(n0 + r) * DMODEL + k0 + c) = o;
}

// ---------------- hybrid: gemm0 (Q/K projection) + mask pack, co-resident ----------------
// Block groups of 8 alternate between gemm (even group) and pack (odd group):
// gemm is MFMA-bound, pack is HBM-bound -> near-free overlap of pack's ~32us.
// gemm lin: z = lin/384, r = lin%384, mb = r/6 (m-panel), nb = r%6 -> 6 consecutive
// blocks share one A f32 panel (L2/L3 reuse).
__global__ __launch_bounds__(256, 3) void k_g0p(
    const float* __restrict__ Af0, const float* __restrict__ Af1,
    const unsigned short* __restrict__ Bt0, const unsigned short* __restrict__ Bt1,
    unsigned short* __restrict__ oQ0, unsigned short* __restrict__ oQ1,
    unsigned short* __restrict__ oT0, unsigned short* __restrict__ oT1,
    const int* __restrict__ mask, unsigned int* __restrict__ mp2) {
  int grpb = blockIdx.x >> 3, t8 = blockIdx.x & 7;
  int lin = (grpb >> 1) * 8 + t8;         // 0..767 within each family
  int tid = threadIdx.x;

  if (grpb & 1) {
    // ---- mask pack: int4 loads + raw-ballot-halves format ----
    // mp2[bh][wi][t], wi = g*8 + k*2 + h holds bit l for column s = g*256 + (h*32+l)*4 + k
    int bh = lin >> 4;                      // 0..47
    int px = lin & 15;                      // 0..15
    int w = tid >> 6, lane = tid & 63;
    int tile4 = px * 4 + w;                 // 0..63
    int rowg = tile4 >> 2, colg = tile4 & 3;
    int t0 = rowg * 64;
    const int* mb = mask + (size_t)bh * S * S + colg * 256;
    unsigned long long b0 = 0, b1 = 0, b2 = 0, b3 = 0;
#pragma unroll 8
    for (int r = 0; r < 64; ++r) {
      int4 v = *reinterpret_cast<const int4*>(mb + (size_t)(t0 + r) * S + lane * 4);
      unsigned long long c0 = __ballot(v.x != 0);
      unsigned long long c1 = __ballot(v.y != 0);
      unsigned long long c2 = __ballot(v.z != 0);
      unsigned long long c3 = __ballot(v.w != 0);
      if (lane == r) { b0 = c0; b1 = c1; b2 = c2; b3 = c3; }
    }
    unsigned int* p2 = mp2 + (size_t)bh * 32 * S + (size_t)(colg * 8) * S + t0 + lane;
    p2[(size_t)0 * S] = (unsigned)b0;  p2[(size_t)1 * S] = (unsigned)(b0 >> 32);
    p2[(size_t)2 * S] = (unsigned)b1;  p2[(size_t)3 * S] = (unsigned)(b1 >> 32);
    p2[(size_t)4 * S] = (unsigned)b2;  p2[(size_t)5 * S] = (unsigned)(b2 >> 32);
    p2[(size_t)6 * S] = (unsigned)b3;  p2[(size_t)7 * S] = (unsigned)(b3 >> 32);
    return;
  }

  // ---- gemm0: 64x128 tile, A f32 reg-staged + cvt_pk_bf16, B bf16 via gl2lds ----
  int z = lin / 384;
  int rr = lin - z * 384;
  int nb = rr % 6, mbp = rr / 6;
  int m0 = mbp * 64, n0 = nb * 128;
  const unsigned short* Bt = z ? Bt1 : Bt0;
  __shared__ __align__(16) unsigned short As[64 * 64];    // 8192 B
  __shared__ __align__(16) unsigned short Bs[128 * 64];   // 16384 B
  int w = tid >> 6, lane = tid & 63, lane15 = lane & 15, quad = lane >> 4;
  int col0 = w * 32;
  f32x4 acc[4][2] = {};

  const unsigned short* gB[4];
  unsigned short* lB[4];
  {
    int lr = lane >> 3, ch = lane & 7;
#pragma unroll
    for (int i = 0; i < 4; ++i) {
      int r = w * 32 + i * 8 + lr;
      int cs = ((ch ^ (r & 7)) * 8);
      gB[i] = Bt + (size_t)(n0 + r) * DMODEL + cs;
      lB[i] = &Bs[(w * 32 + i * 8) * 64];
    }
  }
  int ar = tid >> 2, aj0 = (tid & 3) * 2;          // A: row ar, chunks aj0/aj0+1
  const float* gAf = (z ? Af1 : Af0) + (size_t)(m0 + ar) * DMODEL + aj0 * 8;
  float4 af[4];
#pragma unroll
  for (int q = 0; q < 4; ++q) af[q] = *reinterpret_cast<const float4*>(gAf + q * 4);
  int arx = ar & 7;
  unsigned short* lAw0 = &As[ar * 64 + ((aj0 ^ arx) * 8)];
  unsigned short* lAw1 = &As[ar * 64 + (((aj0 + 1) ^ arx) * 8)];

  // prologue: stage tile 0
#pragma unroll
  for (int i = 0; i < 4; ++i) gl2lds16(gB[i], lB[i]);
  {
    uint4 w0, w1;
    w0.x = pkbf(af[0].x, af[0].y); w0.y = pkbf(af[0].z, af[0].w);
    w0.z = pkbf(af[1].x, af[1].y); w0.w = pkbf(af[1].z, af[1].w);
    w1.x = pkbf(af[2].x, af[2].y); w1.y = pkbf(af[2].z, af[2].w);
    w1.z = pkbf(af[3].x, af[3].y); w1.w = pkbf(af[3].z, af[3].w);
    *reinterpret_cast<uint4*>(lAw0) = w0;
    *reinterpret_cast<uint4*>(lAw1) = w1;
  }

  int l7 = lane15 & 7;
  for (int kc = 0; kc < 12; ++kc) {
    __syncthreads();   // tile kc resident + visible
    if (kc < 11) {
#pragma unroll
      for (int q = 0; q < 4; ++q)
        af[q] = *reinterpret_cast<const float4*>(gAf + (kc + 1) * 64 + q * 4);
    }
#pragma unroll
    for (int ks = 0; ks < 2; ++ks) {
      int co = (((ks * 4 + quad) ^ l7) * 8);
      bf16x8 a[4], b[2];
#pragma unroll
      for (int i = 0; i < 4; ++i) a[i] = ldfrag(&As[(i * 16 + lane15) * 64 + co]);
#pragma unroll
      for (int j = 0; j < 2; ++j) b[j] = ldfrag(&Bs[(col0 + j * 16 + lane15) * 64 + co]);
#pragma unroll
      for (int i = 0; i < 4; ++i)
#pragma unroll
        for (int j = 0; j < 2; ++j)
          acc[i][j] = __builtin_amdgcn_mfma_f32_16x16x32_bf16(a[i], b[j], acc[i][j], 0, 0, 0);
    }
    __syncthreads();   // reads of tile kc done
    if (kc < 11) {
      int ko = (kc + 1) * 64;
#pragma unroll
      for (int i = 0; i < 4; ++i) gl2lds16(gB[i] + ko, lB[i]);
      uint4 w0, w1;
      w0.x = pkbf(af[0].x, af[0].y); w0.y = pkbf(af[0].z, af[0].w);
      w0.z = pkbf(af[1].x, af[1].y); w0.w = pkbf(af[1].z, af[1].w);
      w1.x = pkbf(af[2].x, af[2].y); w1.y = pkbf(af[2].z, af[2].w);
      w1.z = pkbf(af[3].x, af[3].y); w1.w = pkbf(af[3].z, af[3].w);
      *reinterpret_cast<uint4*>(lAw0) = w0;
      *reinterpret_cast<uint4*>(lAw1) = w1;
    }
  }

  unsigned short* out = z ? oQ1 : oQ0;
  unsigned short* outT = z ? oT1 : oT0;
  f16x4 iden;
#pragma unroll
  for (int i = 0; i < 4; ++i) iden[i] = (_Float16)((quad * 4 + i) == lane15 ? 1.0f : 0.0f);
  f32x4 zero4 = {};
#pragma unroll
  for (int i = 0; i < 4; ++i)
#pragma unroll
    for (int j = 0; j < 2; ++j) {
      f16x4 cf;
#pragma unroll
      for (int reg = 0; reg < 4; ++reg) cf[reg] = (_Float16)acc[i][j][reg];
      f32x4 tq = __builtin_amdgcn_mfma_f32_16x16x16f16(cf, iden, zero4, 0, 0, 0);
      {   // Qb store: tq regs = 4 consecutive d, fixed s
        int m = m0 + i * 16 + lane15;
        int n = n0 + col0 + j * 16 + quad * 4;
        int b = m >> 10, s = m & 1023, h = n >> 6, d = n & 63;
        ushort4 o;
        o.x = h2u((_Float16)tq[0]); o.y = h2u((_Float16)tq[1]);
        o.z = h2u((_Float16)tq[2]); o.w = h2u((_Float16)tq[3]);
        *reinterpret_cast<ushort4*>(&out[(((size_t)(b * NH + h)) * S + s) * DK + d]) = o;
      }
      {   // QT store: acc regs = 4 consecutive s, fixed d
        int n = n0 + col0 + j * 16 + lane15;
        int m = m0 + i * 16 + quad * 4;
        int b = m >> 10, s = m & 1023, h = n >> 6, d = n & 63;
        ushort4 o;
        o.x = h2u((_Float16)acc[i][j][0]); o.y = h2u((_Float16)acc[i][j][1]);
        o.z = h2u((_Float16)acc[i][j][2]); o.w = h2u((_Float16)acc[i][j][3]);
        *reinterpret_cast<ushort4*>(&outT[(((size_t)(b * NH + h)) * DK + d) * S + s]) = o;
      }
    }
}

// ---------------- gemm1: 64x128 tile, A bf16 via gl2lds, writes f16 pre-LN ----------------
__global__ __launch_bounds__(256, 3) void k_gemm1(
    const unsigned short* __restrict__ A0, const unsigned short* __restrict__ A1,
    const unsigned short* __restrict__ Bt,
    unsigned short* __restrict__ oH0, unsigned short* __restrict__ oH1) {
  int lin = blockIdx.x;
  int z = lin / 384;
  int rr = lin - z * 384;
  int nb = rr % 6, mbp = rr / 6;
  int m0 = mbp * 64, n0 = nb * 128;
  const unsigned short* A = z ? A1 : A0;
  __shared__ __align__(16) unsigned short As[64 * 64];
  __shared__ __align__(16) unsigned short Bs[128 * 64];
  int tid = threadIdx.x;
  int w = tid >> 6, lane = tid & 63, lane15 = lane & 15, quad = lane >> 4;
  int col0 = w * 32;
  f32x4 acc[4][2] = {};

  const unsigned short* gB[4];
  unsigned short* lB[4];
  const unsigned short* gA[2];
  unsigned short* lA[2];
  {
    int lr = lane >> 3, ch = lane & 7;
#pragma unroll
    for (int i = 0; i < 4; ++i) {
      int r = w * 32 + i * 8 + lr;
      int cs = ((ch ^ (r & 7)) * 8);
      gB[i] = Bt + (size_t)(n0 + r) * DMODEL + cs;
      lB[i] = &Bs[(w * 32 + i * 8) * 64];
    }
#pragma unroll
    for (int i = 0; i < 2; ++i) {
      int r = w * 16 + i * 8 + lr;
      int cs = ((ch ^ (r & 7)) * 8);
      gA[i] = A + (size_t)(m0 + r) * DMODEL + cs;
      lA[i] = &As[(w * 16 + i * 8) * 64];
    }
  }
#pragma unroll
  for (int i = 0; i < 4; ++i) gl2lds16(gB[i], lB[i]);
#pragma unroll
  for (int i = 0; i < 2; ++i) gl2lds16(gA[i], lA[i]);

  int l7 = lane15 & 7;
  for (int kc = 0; kc < 12; ++kc) {
    __syncthreads();
#pragma unroll
    for (int ks = 0; ks < 2; ++ks) {
      int co = (((ks * 4 + quad) ^ l7) * 8);
      bf16x8 a[4], b[2];
#pragma unroll
      for (int i = 0; i < 4; ++i) a[i] = ldfrag(&As[(i * 16 + lane15) * 64 + co]);
#pragma unroll
      for (int j = 0; j < 2; ++j) b[j] = ldfrag(&Bs[(col0 + j * 16 + lane15) * 64 + co]);
#pragma unroll
      for (int i = 0; i < 4; ++i)
#pragma unroll
        for (int j = 0; j < 2; ++j)
          acc[i][j] = __builtin_amdgcn_mfma_f32_16x16x32_bf16(a[i], b[j], acc[i][j], 0, 0, 0);
    }
    __syncthreads();
    if (kc < 11) {
      int ko = (kc + 1) * 64;
#pragma unroll
      for (int i = 0; i < 4; ++i) gl2lds16(gB[i] + ko, lB[i]);
#pragma unroll
      for (int i = 0; i < 2; ++i) gl2lds16(gA[i] + ko, lA[i]);
    }
  }

  unsigned short* outh = z ? oH1 : oH0;
#pragma unroll
  for (int i = 0; i < 4; ++i)
#pragma unroll
    for (int j = 0; j < 2; ++j)
#pragma unroll
      for (int reg = 0; reg < 4; ++reg) {
        int m = m0 + i * 16 + quad * 4 + reg;
        int n = n0 + col0 + j * 16 + lane15;
        outh[(size_t)m * DMODEL + n] = h2u((_Float16)acc[i][j][reg]);
      }
}

// ---------------- fused dual-path attention ----------------
// XCD-bijective remap, double-buffered LDS (1 barrier/chunk), ballot-half mask format,
// cvt_pkrtz packed P->f16, s_setprio around MFMA clusters.
__global__ __launch_bounds__(256, 3) void k_attn(
    const unsigned short* __restrict__ Qb, const unsigned short* __restrict__ Kb,
    const unsigned short* __restrict__ QT, const unsigned short* __restrict__ KT,
    const unsigned int* __restrict__ mp2,
    unsigned short* __restrict__ c1, unsigned short* __restrict__ c2) {
  // XCD-grouped remap (bijective, 768 = 8 XCD * 96)
  int lin = blockIdx.x;
  int xcd = lin & 7, idx = lin >> 3;      // idx 0..95
  int grp = xcd * 12 + (idx >> 3);        // 0..95: (bh,path) group
  int sb = idx & 7;                       // s-block within group
  int path = grp >= 48 ? 1 : 0;
  int bh = grp - path * 48;
  int s0b = sb * 128;

  const unsigned short* X = path ? Kb : Qb;
  const unsigned short* Y = path ? Qb : Kb;
  const unsigned short* YT = path ? QT : KT;
  unsigned short* outc = path ? c2 : c1;

  __shared__ __align__(16) unsigned short YS[2][64 * 72];
  __shared__ __align__(16) unsigned short YTS[2][64 * 72];
  __shared__ __align__(16) unsigned int MWS[2][512];

  const unsigned short* Xb = X + (size_t)bh * S * DK;
  const unsigned short* Yb = Y + (size_t)bh * S * DK;
  const unsigned short* YTb = YT + (size_t)bh * DK * S;
  const unsigned int* mbg = mp2 + (size_t)bh * 32 * S;

  int tid = threadIdx.x;
  int w = tid >> 6, lane = tid & 63, lane15 = lane & 15, quad = lane >> 4;
  int s0w = s0b + w * 32;
  int ck = lane15 & 3;                 // path0 consumer word-select
  int sh0 = w * 8 + (lane15 >> 2);     // path0 consumer shift (rg=0); rg=1 -> +4

  // X fragments (MFMA B-operands for swapped QK)
  f16x8 xf[2][2];
#pragma unroll
  for (int rg = 0; rg < 2; ++rg) {
    xf[rg][0] = ldfragh(Xb + (size_t)(s0w + rg * 16 + lane15) * DK + quad * 8);
    xf[rg][1] = ldfragh(Xb + (size_t)(s0w + rg * 16 + lane15) * DK + 32 + quad * 8);
  }

  // Y/YT staging: thread covers row sr4 (0..63), 16 cols at sc4
  int sr4 = tid >> 2, sc4 = (tid & 3) * 16;
  const unsigned short* gY = Yb + (size_t)sr4 * DK + sc4;
  const unsigned short* gYT = YTb + (size_t)sr4 * S + sc4;
  uint4 y0 = *reinterpret_cast<const uint4*>(gY);
  uint4 y1 = *reinterpret_cast<const uint4*>(gY + 8);
  uint4 t0 = *reinterpret_cast<const uint4*>(gYT);
  uint4 t1 = *reinterpret_cast<const uint4*>(gYT + 8);

  // mask word prefetch (chunk 0)
  int mj = tid >> 2;                   // path0: j-row
  int p0wi = (sb >> 1) * 8 + (tid & 3) * 2 + (sb & 1);   // path0 staging word index
  int tl = tid >> 1;                   // path1: local t
  int k0 = (tid & 1) * 2, k1 = k0 + 1; // path1 staging k's
  unsigned mwv0, mwv1 = 0;
  if (path == 0) {
    mwv0 = mbg[(size_t)p0wi * S + mj];
  } else {
    mwv0 = mbg[(size_t)(k0 * 2) * S + s0b + tl];   // jcn=0 -> wbase=0
    mwv1 = mbg[(size_t)(k1 * 2) * S + s0b + tl];
  }

  f32x4 outa[2][4] = {};
  float lsum[2] = {0.f, 0.f};

  for (int jc = 0; jc < 16; ++jc) {
    int buf = jc & 1;
    // stage chunk jc (regs -> LDS[buf]); safe: concurrent compute is jc-1 on buf^1
    *reinterpret_cast<uint4*>(&YS[buf][sr4 * 72 + sc4]) = y0;
    *reinterpret_cast<uint4*>(&YS[buf][sr4 * 72 + sc4 + 8]) = y1;
    *reinterpret_cast<uint4*>(&YTS[buf][sr4 * 72 + sc4]) = t0;
    *reinterpret_cast<uint4*>(&YTS[buf][sr4 * 72 + sc4 + 8]) = t1;
    if (path == 0) {
      MWS[buf][tid] = mwv0;            // idx = j*4 + k = tid
    } else {
      uint2 mw; mw.x = mwv0; mw.y = mwv1;
      *reinterpret_cast<uint2*>(&MWS[buf][tid * 2]) = mw;   // (tl, k0),(tl, k1)
    }
    // prefetch chunk jc+1 (clamped)
    {
      int jcn = (jc + 1 < 16) ? jc + 1 : jc;
      int jn = jcn * 64;
      y0 = *reinterpret_cast<const uint4*>(gY + (size_t)jn * DK);
      y1 = *reinterpret_cast<const uint4*>(gY + (size_t)jn * DK + 8);
      t0 = *reinterpret_cast<const uint4*>(gYT + jn);
      t1 = *reinterpret_cast<const uint4*>(gYT + jn + 8);
      if (path == 0) {
        mwv0 = mbg[(size_t)p0wi * S + jn + mj];
      } else {
        size_t wb = (size_t)((jcn >> 2) * 8 + ((jcn >> 1) & 1)) * S + s0b + tl;
        mwv0 = mbg[wb + (size_t)(k0 * 2) * S];
        mwv1 = mbg[wb + (size_t)(k1 * 2) * S];
      }
    }
    __syncthreads();   // chunk jc resident for all waves

    // swapped QK: S^T[j][s] frags, C(row=j=quad*4+reg, col=s=lane15)
    f32x4 scv[4][2];
    __builtin_amdgcn_s_setprio(1);
#pragma unroll
    for (int st = 0; st < 4; ++st) {
      f16x8 a0 = ldfragh(&YS[buf][(st * 16 + lane15) * 72 + quad * 8]);
      f16x8 a1 = ldfragh(&YS[buf][(st * 16 + lane15) * 72 + 32 + quad * 8]);
#pragma unroll
      for (int rg = 0; rg < 2; ++rg) {
        f32x4 v = {};
        v = __builtin_amdgcn_mfma_f32_16x16x32_f16(a0, xf[rg][0], v, 0, 0, 0);
        v = __builtin_amdgcn_mfma_f32_16x16x32_f16(a1, xf[rg][1], v, 0, 0, 0);
        scv[st][rg] = v;
      }
    }
    __builtin_amdgcn_s_setprio(0);
    // mask + exp; P^T frags feed PV directly
    f16x4 pfa[4][2];
    if (path == 0) {
#pragma unroll
      for (int st = 0; st < 4; ++st) {
        float pv[2][4];
#pragma unroll
        for (int reg = 0; reg < 4; ++reg) {
          unsigned wdv = MWS[buf][(st * 16 + quad * 4 + reg) * 4 + ck];
#pragma unroll
          for (int rg = 0; rg < 2; ++rg) {
            float e = __expf(scv[st][rg][reg] * 0.125f);
            float p = ((wdv >> (unsigned)(sh0 + rg * 4)) & 1u) ? 0.f : e;
            lsum[rg] += p;
            pv[rg][reg] = p;
          }
        }
        pfa[st][0] = pack4(pv[0]);
        pfa[st][1] = pack4(pv[1]);
      }
    } else {
#pragma unroll
      for (int rg = 0; rg < 2; ++rg) {
        int bidx = (w * 32 + rg * 16 + lane15) * 4;
        uint4 wq = *reinterpret_cast<const uint4*>(&MWS[buf][bidx]);
        unsigned wd4[4] = {wq.x, wq.y, wq.z, wq.w};
#pragma unroll
        for (int st = 0; st < 4; ++st) {
          float pv[4];
          unsigned shb = (unsigned)((jc & 1) * 16 + st * 4 + quad);
#pragma unroll
          for (int reg = 0; reg < 4; ++reg) {
            float e = __expf(scv[st][rg][reg] * 0.125f);
            float p = ((wd4[reg] >> shb) & 1u) ? 0.f : e;
            lsum[rg] += p;
            pv[reg] = p;
          }
          pfa[st][rg] = pack4(pv);
        }
      }
    }
    // PV: outa[rg][dsub] += P^T_frag (A) x Y (B from YTS, b64 reads)
    __builtin_amdgcn_s_setprio(1);
#pragma unroll
    for (int st = 0; st < 4; ++st)
#pragma unroll
      for (int dsub = 0; dsub < 4; ++dsub) {
        uint2 q = *reinterpret_cast<const uint2*>(&YTS[buf][(dsub * 16 + lane15) * 72 + st * 16 + quad * 4]);
        f16x4 yb = __builtin_bit_cast(f16x4, q);
#pragma unroll
        for (int rg = 0; rg < 2; ++rg)
          outa[rg][dsub] = __builtin_amdgcn_mfma_f32_16x16x16f16(pfa[st][rg], yb, outa[rg][dsub], 0, 0, 0);
      }
    __builtin_amdgcn_s_setprio(0);
  }

  // row sums: reduce across quads
#pragma unroll
  for (int rg = 0; rg < 2; ++rg) {
    lsum[rg] += __shfl_xor(lsum[rg], 16);
    lsum[rg] += __shfl_xor(lsum[rg], 32);
  }
  float rinv[2][4];
#pragma unroll
  for (int rg = 0; rg < 2; ++rg)
#pragma unroll
    for (int reg = 0; reg < 4; ++reg)
      rinv[rg][reg] = 1.0f / __shfl(lsum[rg], quad * 4 + reg);

  int b = bh / NH, h = bh % NH;
#pragma unroll
  for (int rg = 0; rg < 2; ++rg)
#pragma unroll
    for (int dsub = 0; dsub < 4; ++dsub)
#pragma unroll
      for (int reg = 0; reg < 4; ++reg) {
        float v = outa[rg][dsub][reg] * rinv[rg][reg];
        int srow = s0w + rg * 16 + quad * 4 + reg;
        size_t idxo = ((size_t)(b * S) + srow) * DMODEL + h * DK + dsub * 16 + lane15;
        outc[idxo] = f2bf(v);
      }
}

// ---------------- LayerNorm over 768 (f16 input), one block per row ----------------
__global__ __launch_bounds__(256) void k_ln(const unsigned short* __restrict__ f1,
                                            const unsigned short* __restrict__ f2,
                                            const float* __restrict__ g1, const float* __restrict__ b1,
                                            const float* __restrict__ g2, const float* __restrict__ b2,
                                            float* __restrict__ out) {
  int rowg = blockIdx.x;
  int sel = rowg >> 12;
  int row = rowg & 4095;
  const unsigned short* in = sel ? f2 : f1;
  const float* g = sel ? g2 : g1;
  const float* be = sel ? b2 : b1;
  int tid = threadIdx.x;
  const unsigned short* p = in + (size_t)row * DMODEL;
  float x0 = (float)__builtin_bit_cast(_Float16, p[tid]);
  float x1 = (float)__builtin_bit_cast(_Float16, p[tid + 256]);
  float x2 = (float)__builtin_bit_cast(_Float16, p[tid + 512]);
  float s = x0 + x1 + x2;
  float ss = x0 * x0 + x1 * x1 + x2 * x2;
#pragma unroll
  for (int m = 1; m < 64; m <<= 1) { s += __shfl_xor(s, m); ss += __shfl_xor(ss, m); }
  __shared__ float ps[4], pss[4];
  int w = tid >> 6;
  if ((tid & 63) == 0) { ps[w] = s; pss[w] = ss; }
  __syncthreads();
  s = ps[0] + ps[1] + ps[2] + ps[3];
  ss = pss[0] + pss[1] + pss[2] + pss[3];
  float mu = s * (1.0f / 768.0f);
  float var = ss * (1.0f / 768.0f) - mu * mu;
  float rstd = rsqrtf(var + 1e-5f);
  float* o = out + ((size_t)sel * M4 + row) * DMODEL;
  o[tid] = (x0 - mu) * rstd * g[tid] + be[tid];
  o[tid + 256] = (x1 - mu) * rstd * g[tid + 256] + be[tid + 256];
  o[tid + 512] = (x2 - mu) * rstd * g[tid + 512] + be[tid + 512];
}

extern "C" void kernel_launch(void* const* d_in, const int* in_sizes, int n_in,
                              void* d_out, int out_size, void* d_ws, size_t ws_size,
                              hipStream_t stream) {
  const float* pro1 = (const float*)d_in[0];
  const float* pro2 = (const float*)d_in[1];
  const int* mask = (const int*)d_in[2];
  const float* WQ = (const float*)d_in[3];
  const float* WK = (const float*)d_in[4];
  const float* FC1 = (const float*)d_in[5];
  const float* g1 = (const float*)d_in[6];
  const float* b1 = (const float*)d_in[7];
  const float* g2 = (const float*)d_in[8];
  const float* b2 = (const float*)d_in[9];
  float* out = (float*)d_out;
  char* ws = (char*)d_ws;

  // workspace layout (bytes)
  unsigned short* f1h = (unsigned short*)(ws + 0);            // 6291456 f16 (pre-LN path1)
  unsigned short* wqt = (unsigned short*)(ws + 12582912);     // 1179648
  unsigned short* wkt = (unsigned short*)(ws + 13762560);     // 1179648
  unsigned short* fc1t = (unsigned short*)(ws + 14942208);    // 1179648
  unsigned short* Qb = (unsigned short*)(ws + 16121856);      // 6291456 f16 [bh][s][d]
  unsigned short* Kb = (unsigned short*)(ws + 22413312);      // 6291456 f16
  unsigned short* QT = (unsigned short*)(ws + 28704768);      // 6291456 f16 [bh][d][s]
  unsigned short* KT = (unsigned short*)(ws + 34996224);      // 6291456 f16
  unsigned int* mp2 = (unsigned int*)(ws + 41287680);         // 6291456
  unsigned short* f2h = (unsigned short*)(ws + 47579136);     // 6291456 f16
  unsigned short* c1 = (unsigned short*)(ws + 60162048);      // 6291456 bf16
  unsigned short* c2 = (unsigned short*)(ws + 66453504);      // 6291456 bf16

  k_prep<<<1728, 256, 0, stream>>>(WQ, WK, FC1, wqt, wkt, fc1t);
  k_g0p<<<1536, 256, 0, stream>>>(pro1, pro2, wqt, wkt, Qb, Kb, QT, KT, mask, mp2);
  k_attn<<<dim3(768), 256, 0, stream>>>(Qb, Kb, QT, KT, mp2, c1, c2);
  k_gemm1<<<768, 256, 0, stream>>>(c1, c2, fc1t, f1h, f2h);
  k_ln<<<8192, 256, 0, stream>>>(f1h, f2h, g1, b1, g2, b2, out);
}

// Round 5
// 401.113 us; speedup vs baseline: 1.0441x; 1.0163x over previous
//
#include <hip/hip_runtime.h>
#include <hip/hip_bf16.h>
#include <stdint.h>

// Problem constants
#define S 1024
#define DMODEL 768
#define NH 12
#define DK 64
#define BB 4
#define BH 48      // BB*NH
#define M4 4096    // BB*S

typedef __attribute__((ext_vector_type(8))) short bf16x8;
typedef __attribute__((ext_vector_type(4))) float f32x4;
typedef __attribute__((ext_vector_type(4))) _Float16 f16x4;
typedef __attribute__((ext_vector_type(8))) _Float16 f16x8;

static __device__ __forceinline__ unsigned short f2bf(float f) {
  unsigned int u = __float_as_uint(f);
  unsigned int r = u + 0x7FFFu + ((u >> 16) & 1u);   // RNE
  return (unsigned short)(r >> 16);
}
// packed f32 pair -> bf16x2 dword (v_cvt_pk_bf16_f32, RNE); low16 = a
static __device__ __forceinline__ unsigned pkbf(float a, float b) {
  unsigned r;
  asm("v_cvt_pk_bf16_f32 %0, %1, %2" : "=v"(r) : "v"(a), "v"(b));
  return r;
}
static __device__ __forceinline__ bf16x8 ldfrag(const unsigned short* p) {
  uint4 q = *reinterpret_cast<const uint4*>(p);
  return __builtin_bit_cast(bf16x8, q);
}
static __device__ __forceinline__ f16x8 ldfragh(const unsigned short* p) {
  uint4 q = *reinterpret_cast<const uint4*>(p);
  return __builtin_bit_cast(f16x8, q);
}
static __device__ __forceinline__ unsigned short h2u(_Float16 h) {
  return __builtin_bit_cast(unsigned short, h);
}
// packed f32x4 -> f16x4 via v_cvt_pkrtz
static __device__ __forceinline__ f16x4 pack4(const float* p) {
  auto lo = __builtin_amdgcn_cvt_pkrtz(p[0], p[1]);   // __fp16 ext_vector(2)
  auto hi = __builtin_amdgcn_cvt_pkrtz(p[2], p[3]);
  uint2 u;
  u.x = __builtin_bit_cast(unsigned int, lo);
  u.y = __builtin_bit_cast(unsigned int, hi);
  return __builtin_bit_cast(f16x4, u);
}
// exp(x/8) with single pre-mul: v_exp_f32 computes 2^x
static __device__ __forceinline__ float exp8(float x) {
#if __has_builtin(__builtin_amdgcn_exp2f)
  return __builtin_amdgcn_exp2f(x * 0.18033688011112042f);   // 0.125*log2(e)
#else
  return __expf(x * 0.125f);
#endif
}
// async global->LDS, 16B per lane; LDS dest = wave-uniform base + lane*16
static __device__ __forceinline__ void gl2lds16(const unsigned short* g, unsigned short* l) {
  __builtin_amdgcn_global_load_lds(
      (const __attribute__((address_space(1))) unsigned int*)g,
      (__attribute__((address_space(3))) unsigned int*)l, 16, 0, 0);
}

// ---------------- prep: W [k][n] f32 -> Wt [n][k] bf16 (3x 768x768) ----------------
__global__ __launch_bounds__(256) void k_prep(const float* __restrict__ w0, const float* __restrict__ w1,
                                              const float* __restrict__ w2,
                                              unsigned short* __restrict__ o0, unsigned short* __restrict__ o1,
                                              unsigned short* __restrict__ o2) {
  int bid = blockIdx.x;
  int tid = threadIdx.x;
  int z = bid / 576;
  int r2 = bid - z * 576;
  int bx = r2 % 24, by = r2 / 24;
  const float* in = z == 0 ? w0 : (z == 1 ? w1 : w2);
  unsigned short* out = z == 0 ? o0 : (z == 1 ? o1 : o2);
  __shared__ float tile[32][33];
  int n0 = bx * 32, k0 = by * 32;
  int r = tid >> 3, c = (tid & 7) * 4;
  float4 v = *reinterpret_cast<const float4*>(in + (size_t)(k0 + r) * DMODEL + n0 + c);
  tile[r][c] = v.x; tile[r][c + 1] = v.y; tile[r][c + 2] = v.z; tile[r][c + 3] = v.w;
  __syncthreads();
  ushort4 o;
  o.x = f2bf(tile[c + 0][r]);
  o.y = f2bf(tile[c + 1][r]);
  o.z = f2bf(tile[c + 2][r]);
  o.w = f2bf(tile[c + 3][r]);
  *reinterpret_cast<ushort4*>(out + (size_t)(n0 + r) * DMODEL + k0 + c) = o;
}

// ---------------- hybrid: gemm0 (Q/K projection) + mask pack, co-resident ----------------
__global__ __launch_bounds__(256, 3) void k_g0p(
    const float* __restrict__ Af0, const float* __restrict__ Af1,
    const unsigned short* __restrict__ Bt0, const unsigned short* __restrict__ Bt1,
    unsigned short* __restrict__ oQ0, unsigned short* __restrict__ oQ1,
    unsigned short* __restrict__ oT0, unsigned short* __restrict__ oT1,
    const int* __restrict__ mask, unsigned int* __restrict__ mp2) {
  int grpb = blockIdx.x >> 3, t8 = blockIdx.x & 7;
  int lin = (grpb >> 1) * 8 + t8;         // 0..767 within each family
  int tid = threadIdx.x;

  if (grpb & 1) {
    // ---- mask pack: int4 loads + raw-ballot-halves format ----
    int bh = lin >> 4;                      // 0..47
    int px = lin & 15;                      // 0..15
    int w = tid >> 6, lane = tid & 63;
    int tile4 = px * 4 + w;                 // 0..63
    int rowg = tile4 >> 2, colg = tile4 & 3;
    int t0 = rowg * 64;
    const int* mb = mask + (size_t)bh * S * S + colg * 256;
    unsigned long long b0 = 0, b1 = 0, b2 = 0, b3 = 0;
#pragma unroll 8
    for (int r = 0; r < 64; ++r) {
      int4 v = *reinterpret_cast<const int4*>(mb + (size_t)(t0 + r) * S + lane * 4);
      unsigned long long c0 = __ballot(v.x != 0);
      unsigned long long c1 = __ballot(v.y != 0);
      unsigned long long c2 = __ballot(v.z != 0);
      unsigned long long c3 = __ballot(v.w != 0);
      if (lane == r) { b0 = c0; b1 = c1; b2 = c2; b3 = c3; }
    }
    unsigned int* p2 = mp2 + (size_t)bh * 32 * S + (size_t)(colg * 8) * S + t0 + lane;
    p2[(size_t)0 * S] = (unsigned)b0;  p2[(size_t)1 * S] = (unsigned)(b0 >> 32);
    p2[(size_t)2 * S] = (unsigned)b1;  p2[(size_t)3 * S] = (unsigned)(b1 >> 32);
    p2[(size_t)4 * S] = (unsigned)b2;  p2[(size_t)5 * S] = (unsigned)(b2 >> 32);
    p2[(size_t)6 * S] = (unsigned)b3;  p2[(size_t)7 * S] = (unsigned)(b3 >> 32);
    return;
  }

  // ---- gemm0: 64x128 tile, A f32 reg-staged + cvt_pk_bf16, B bf16 via gl2lds ----
  int z = lin / 384;
  int rr = lin - z * 384;
  int nb = rr % 6, mbp = rr / 6;
  int m0 = mbp * 64, n0 = nb * 128;
  const unsigned short* Bt = z ? Bt1 : Bt0;
  __shared__ __align__(16) unsigned short As[64 * 64];    // 8192 B
  __shared__ __align__(16) unsigned short Bs[128 * 64];   // 16384 B
  int w = tid >> 6, lane = tid & 63, lane15 = lane & 15, quad = lane >> 4;
  int col0 = w * 32;
  f32x4 acc[4][2] = {};

  const unsigned short* gB[4];
  unsigned short* lB[4];
  {
    int lr = lane >> 3, ch = lane & 7;
#pragma unroll
    for (int i = 0; i < 4; ++i) {
      int r = w * 32 + i * 8 + lr;
      int cs = ((ch ^ (r & 7)) * 8);
      gB[i] = Bt + (size_t)(n0 + r) * DMODEL + cs;
      lB[i] = &Bs[(w * 32 + i * 8) * 64];
    }
  }
  int ar = tid >> 2, aj0 = (tid & 3) * 2;          // A: row ar, chunks aj0/aj0+1
  const float* gAf = (z ? Af1 : Af0) + (size_t)(m0 + ar) * DMODEL + aj0 * 8;
  float4 af[4];
#pragma unroll
  for (int q = 0; q < 4; ++q) af[q] = *reinterpret_cast<const float4*>(gAf + q * 4);
  int arx = ar & 7;
  unsigned short* lAw0 = &As[ar * 64 + ((aj0 ^ arx) * 8)];
  unsigned short* lAw1 = &As[ar * 64 + (((aj0 + 1) ^ arx) * 8)];

  // prologue: stage tile 0
#pragma unroll
  for (int i = 0; i < 4; ++i) gl2lds16(gB[i], lB[i]);
  {
    uint4 w0, w1;
    w0.x = pkbf(af[0].x, af[0].y); w0.y = pkbf(af[0].z, af[0].w);
    w0.z = pkbf(af[1].x, af[1].y); w0.w = pkbf(af[1].z, af[1].w);
    w1.x = pkbf(af[2].x, af[2].y); w1.y = pkbf(af[2].z, af[2].w);
    w1.z = pkbf(af[3].x, af[3].y); w1.w = pkbf(af[3].z, af[3].w);
    *reinterpret_cast<uint4*>(lAw0) = w0;
    *reinterpret_cast<uint4*>(lAw1) = w1;
  }

  int l7 = lane15 & 7;
  for (int kc = 0; kc < 12; ++kc) {
    __syncthreads();   // tile kc resident + visible
    if (kc < 11) {
#pragma unroll
      for (int q = 0; q < 4; ++q)
        af[q] = *reinterpret_cast<const float4*>(gAf + (kc + 1) * 64 + q * 4);
    }
#pragma unroll
    for (int ks = 0; ks < 2; ++ks) {
      int co = (((ks * 4 + quad) ^ l7) * 8);
      bf16x8 a[4], b[2];
#pragma unroll
      for (int i = 0; i < 4; ++i) a[i] = ldfrag(&As[(i * 16 + lane15) * 64 + co]);
#pragma unroll
      for (int j = 0; j < 2; ++j) b[j] = ldfrag(&Bs[(col0 + j * 16 + lane15) * 64 + co]);
#pragma unroll
      for (int i = 0; i < 4; ++i)
#pragma unroll
        for (int j = 0; j < 2; ++j)
          acc[i][j] = __builtin_amdgcn_mfma_f32_16x16x32_bf16(a[i], b[j], acc[i][j], 0, 0, 0);
    }
    __syncthreads();   // reads of tile kc done
    if (kc < 11) {
      int ko = (kc + 1) * 64;
#pragma unroll
      for (int i = 0; i < 4; ++i) gl2lds16(gB[i] + ko, lB[i]);
      uint4 w0, w1;
      w0.x = pkbf(af[0].x, af[0].y); w0.y = pkbf(af[0].z, af[0].w);
      w0.z = pkbf(af[1].x, af[1].y); w0.w = pkbf(af[1].z, af[1].w);
      w1.x = pkbf(af[2].x, af[2].y); w1.y = pkbf(af[2].z, af[2].w);
      w1.z = pkbf(af[3].x, af[3].y); w1.w = pkbf(af[3].z, af[3].w);
      *reinterpret_cast<uint4*>(lAw0) = w0;
      *reinterpret_cast<uint4*>(lAw1) = w1;
    }
  }

  unsigned short* out = z ? oQ1 : oQ0;
  unsigned short* outT = z ? oT1 : oT0;
  f16x4 iden;
#pragma unroll
  for (int i = 0; i < 4; ++i) iden[i] = (_Float16)((quad * 4 + i) == lane15 ? 1.0f : 0.0f);
  f32x4 zero4 = {};
#pragma unroll
  for (int i = 0; i < 4; ++i)
#pragma unroll
    for (int j = 0; j < 2; ++j) {
      f16x4 cf;
#pragma unroll
      for (int reg = 0; reg < 4; ++reg) cf[reg] = (_Float16)acc[i][j][reg];
      f32x4 tq = __builtin_amdgcn_mfma_f32_16x16x16f16(cf, iden, zero4, 0, 0, 0);
      {   // Qb store: tq regs = 4 consecutive d, fixed s
        int m = m0 + i * 16 + lane15;
        int n = n0 + col0 + j * 16 + quad * 4;
        int b = m >> 10, s = m & 1023, h = n >> 6, d = n & 63;
        ushort4 o;
        o.x = h2u((_Float16)tq[0]); o.y = h2u((_Float16)tq[1]);
        o.z = h2u((_Float16)tq[2]); o.w = h2u((_Float16)tq[3]);
        *reinterpret_cast<ushort4*>(&out[(((size_t)(b * NH + h)) * S + s) * DK + d]) = o;
      }
      {   // QT store: acc regs = 4 consecutive s, fixed d
        int n = n0 + col0 + j * 16 + lane15;
        int m = m0 + i * 16 + quad * 4;
        int b = m >> 10, s = m & 1023, h = n >> 6, d = n & 63;
        ushort4 o;
        o.x = h2u((_Float16)acc[i][j][0]); o.y = h2u((_Float16)acc[i][j][1]);
        o.z = h2u((_Float16)acc[i][j][2]); o.w = h2u((_Float16)acc[i][j][3]);
        *reinterpret_cast<ushort4*>(&outT[(((size_t)(b * NH + h)) * DK + d) * S + s]) = o;
      }
    }
}

// ---------------- gemm1: 64x128 tile, A bf16 via gl2lds, writes f16 pre-LN ----------------
__global__ __launch_bounds__(256, 3) void k_gemm1(
    const unsigned short* __restrict__ A0, const unsigned short* __restrict__ A1,
    const unsigned short* __restrict__ Bt,
    unsigned short* __restrict__ oH0, unsigned short* __restrict__ oH1) {
  int lin = blockIdx.x;
  int z = lin / 384;
  int rr = lin - z * 384;
  int nb = rr % 6, mbp = rr / 6;
  int m0 = mbp * 64, n0 = nb * 128;
  const unsigned short* A = z ? A1 : A0;
  __shared__ __align__(16) unsigned short As[64 * 64];
  __shared__ __align__(16) unsigned short Bs[128 * 64];
  int tid = threadIdx.x;
  int w = tid >> 6, lane = tid & 63, lane15 = lane & 15, quad = lane >> 4;
  int col0 = w * 32;
  f32x4 acc[4][2] = {};

  const unsigned short* gB[4];
  unsigned short* lB[4];
  const unsigned short* gA[2];
  unsigned short* lA[2];
  {
    int lr = lane >> 3, ch = lane & 7;
#pragma unroll
    for (int i = 0; i < 4; ++i) {
      int r = w * 32 + i * 8 + lr;
      int cs = ((ch ^ (r & 7)) * 8);
      gB[i] = Bt + (size_t)(n0 + r) * DMODEL + cs;
      lB[i] = &Bs[(w * 32 + i * 8) * 64];
    }
#pragma unroll
    for (int i = 0; i < 2; ++i) {
      int r = w * 16 + i * 8 + lr;
      int cs = ((ch ^ (r & 7)) * 8);
      gA[i] = A + (size_t)(m0 + r) * DMODEL + cs;
      lA[i] = &As[(w * 16 + i * 8) * 64];
    }
  }
#pragma unroll
  for (int i = 0; i < 4; ++i) gl2lds16(gB[i], lB[i]);
#pragma unroll
  for (int i = 0; i < 2; ++i) gl2lds16(gA[i], lA[i]);

  int l7 = lane15 & 7;
  for (int kc = 0; kc < 12; ++kc) {
    __syncthreads();
#pragma unroll
    for (int ks = 0; ks < 2; ++ks) {
      int co = (((ks * 4 + quad) ^ l7) * 8);
      bf16x8 a[4], b[2];
#pragma unroll
      for (int i = 0; i < 4; ++i) a[i] = ldfrag(&As[(i * 16 + lane15) * 64 + co]);
#pragma unroll
      for (int j = 0; j < 2; ++j) b[j] = ldfrag(&Bs[(col0 + j * 16 + lane15) * 64 + co]);
#pragma unroll
      for (int i = 0; i < 4; ++i)
#pragma unroll
        for (int j = 0; j < 2; ++j)
          acc[i][j] = __builtin_amdgcn_mfma_f32_16x16x32_bf16(a[i], b[j], acc[i][j], 0, 0, 0);
    }
    __syncthreads();
    if (kc < 11) {
      int ko = (kc + 1) * 64;
#pragma unroll
      for (int i = 0; i < 4; ++i) gl2lds16(gB[i] + ko, lB[i]);
#pragma unroll
      for (int i = 0; i < 2; ++i) gl2lds16(gA[i] + ko, lA[i]);
    }
  }

  unsigned short* outh = z ? oH1 : oH0;
#pragma unroll
  for (int i = 0; i < 4; ++i)
#pragma unroll
    for (int j = 0; j < 2; ++j)
#pragma unroll
      for (int reg = 0; reg < 4; ++reg) {
        int m = m0 + i * 16 + quad * 4 + reg;
        int n = n0 + col0 + j * 16 + lane15;
        outh[(size_t)m * DMODEL + n] = h2u((_Float16)acc[i][j][reg]);
      }
}

// ---------------- fused dual-path attention ----------------
// XCD-bijective remap, double-buffered LDS (1 barrier/chunk), ballot-half mask format,
// cvt_pkrtz packed P->f16, s_setprio around MFMA clusters, MFMA-ones row-sums
// (removes the 32-add serial lsum chain + end shuffles), exp2-folded exp.
__global__ __launch_bounds__(256, 3) void k_attn(
    const unsigned short* __restrict__ Qb, const unsigned short* __restrict__ Kb,
    const unsigned short* __restrict__ QT, const unsigned short* __restrict__ KT,
    const unsigned int* __restrict__ mp2,
    unsigned short* __restrict__ c1, unsigned short* __restrict__ c2) {
  // XCD-grouped remap (bijective, 768 = 8 XCD * 96)
  int lin = blockIdx.x;
  int xcd = lin & 7, idx = lin >> 3;      // idx 0..95
  int grp = xcd * 12 + (idx >> 3);        // 0..95: (bh,path) group
  int sb = idx & 7;                       // s-block within group
  int path = grp >= 48 ? 1 : 0;
  int bh = grp - path * 48;
  int s0b = sb * 128;

  const unsigned short* X = path ? Kb : Qb;
  const unsigned short* Y = path ? Qb : Kb;
  const unsigned short* YT = path ? QT : KT;
  unsigned short* outc = path ? c2 : c1;

  __shared__ __align__(16) unsigned short YS[2][64 * 72];
  __shared__ __align__(16) unsigned short YTS[2][64 * 72];
  __shared__ __align__(16) unsigned int MWS[2][512];

  const unsigned short* Xb = X + (size_t)bh * S * DK;
  const unsigned short* Yb = Y + (size_t)bh * S * DK;
  const unsigned short* YTb = YT + (size_t)bh * DK * S;
  const unsigned int* mbg = mp2 + (size_t)bh * 32 * S;

  int tid = threadIdx.x;
  int w = tid >> 6, lane = tid & 63, lane15 = lane & 15, quad = lane >> 4;
  int s0w = s0b + w * 32;
  int ck = lane15 & 3;                 // path0 consumer word-select
  int sh0 = w * 8 + (lane15 >> 2);     // path0 consumer shift (rg=0); rg=1 -> +4

  // X fragments (MFMA B-operands for swapped QK)
  f16x8 xf[2][2];
#pragma unroll
  for (int rg = 0; rg < 2; ++rg) {
    xf[rg][0] = ldfragh(Xb + (size_t)(s0w + rg * 16 + lane15) * DK + quad * 8);
    xf[rg][1] = ldfragh(Xb + (size_t)(s0w + rg * 16 + lane15) * DK + 32 + quad * 8);
  }

  // Y/YT staging: thread covers row sr4 (0..63), 16 cols at sc4
  int sr4 = tid >> 2, sc4 = (tid & 3) * 16;
  const unsigned short* gY = Yb + (size_t)sr4 * DK + sc4;
  const unsigned short* gYT = YTb + (size_t)sr4 * S + sc4;
  uint4 y0 = *reinterpret_cast<const uint4*>(gY);
  uint4 y1 = *reinterpret_cast<const uint4*>(gY + 8);
  uint4 t0 = *reinterpret_cast<const uint4*>(gYT);
  uint4 t1 = *reinterpret_cast<const uint4*>(gYT + 8);

  // mask word prefetch (chunk 0)
  int mj = tid >> 2;                   // path0: j-row
  int p0wi = (sb >> 1) * 8 + (tid & 3) * 2 + (sb & 1);   // path0 staging word index
  int tl = tid >> 1;                   // path1: local t
  int k0 = (tid & 1) * 2, k1 = k0 + 1; // path1 staging k's
  unsigned mwv0, mwv1 = 0;
  if (path == 0) {
    mwv0 = mbg[(size_t)p0wi * S + mj];
  } else {
    mwv0 = mbg[(size_t)(k0 * 2) * S + s0b + tl];   // jcn=0 -> wbase=0
    mwv1 = mbg[(size_t)(k1 * 2) * S + s0b + tl];
  }

  f32x4 outa[2][4] = {};
  f32x4 outs[2] = {};                  // MFMA row-sums (vs ones)
  f16x4 onesf;
#pragma unroll
  for (int i = 0; i < 4; ++i) onesf[i] = (_Float16)1.0f;

  for (int jc = 0; jc < 16; ++jc) {
    int buf = jc & 1;
    // stage chunk jc (regs -> LDS[buf]); safe: concurrent compute is jc-1 on buf^1
    *reinterpret_cast<uint4*>(&YS[buf][sr4 * 72 + sc4]) = y0;
    *reinterpret_cast<uint4*>(&YS[buf][sr4 * 72 + sc4 + 8]) = y1;
    *reinterpret_cast<uint4*>(&YTS[buf][sr4 * 72 + sc4]) = t0;
    *reinterpret_cast<uint4*>(&YTS[buf][sr4 * 72 + sc4 + 8]) = t1;
    if (path == 0) {
      MWS[buf][tid] = mwv0;            // idx = j*4 + k = tid
    } else {
      uint2 mw; mw.x = mwv0; mw.y = mwv1;
      *reinterpret_cast<uint2*>(&MWS[buf][tid * 2]) = mw;   // (tl, k0),(tl, k1)
    }
    // prefetch chunk jc+1 (clamped)
    {
      int jcn = (jc + 1 < 16) ? jc + 1 : jc;
      int jn = jcn * 64;
      y0 = *reinterpret_cast<const uint4*>(gY + (size_t)jn * DK);
      y1 = *reinterpret_cast<const uint4*>(gY + (size_t)jn * DK + 8);
      t0 = *reinterpret_cast<const uint4*>(gYT + jn);
      t1 = *reinterpret_cast<const uint4*>(gYT + jn + 8);
      if (path == 0) {
        mwv0 = mbg[(size_t)p0wi * S + jn + mj];
      } else {
        size_t wb = (size_t)((jcn >> 2) * 8 + ((jcn >> 1) & 1)) * S + s0b + tl;
        mwv0 = mbg[wb + (size_t)(k0 * 2) * S];
        mwv1 = mbg[wb + (size_t)(k1 * 2) * S];
      }
    }
    __syncthreads();   // chunk jc resident for all waves

    // swapped QK: S^T[j][s] frags, C(row=j=quad*4+reg, col=s=lane15)
    f32x4 scv[4][2];
    __builtin_amdgcn_s_setprio(1);
#pragma unroll
    for (int st = 0; st < 4; ++st) {
      f16x8 a0 = ldfragh(&YS[buf][(st * 16 + lane15) * 72 + quad * 8]);
      f16x8 a1 = ldfragh(&YS[buf][(st * 16 + lane15) * 72 + 32 + quad * 8]);
#pragma unroll
      for (int rg = 0; rg < 2; ++rg) {
        f32x4 v = {};
        v = __builtin_amdgcn_mfma_f32_16x16x32_f16(a0, xf[rg][0], v, 0, 0, 0);
        v = __builtin_amdgcn_mfma_f32_16x16x32_f16(a1, xf[rg][1], v, 0, 0, 0);
        scv[st][rg] = v;
      }
    }
    __builtin_amdgcn_s_setprio(0);
    // mask + exp; P^T frags feed PV directly (no serial lsum chain)
    f16x4 pfa[4][2];
    if (path == 0) {
#pragma unroll
      for (int st = 0; st < 4; ++st) {
        float pv[2][4];
#pragma unroll
        for (int reg = 0; reg < 4; ++reg) {
          unsigned wdv = MWS[buf][(st * 16 + quad * 4 + reg) * 4 + ck];
#pragma unroll
          for (int rg = 0; rg < 2; ++rg) {
            float e = exp8(scv[st][rg][reg]);
            pv[rg][reg] = ((wdv >> (unsigned)(sh0 + rg * 4)) & 1u) ? 0.f : e;
          }
        }
        pfa[st][0] = pack4(pv[0]);
        pfa[st][1] = pack4(pv[1]);
      }
    } else {
#pragma unroll
      for (int rg = 0; rg < 2; ++rg) {
        int bidx = (w * 32 + rg * 16 + lane15) * 4;
        uint4 wq = *reinterpret_cast<const uint4*>(&MWS[buf][bidx]);
        unsigned wd4[4] = {wq.x, wq.y, wq.z, wq.w};
#pragma unroll
        for (int st = 0; st < 4; ++st) {
          float pv[4];
          unsigned shb = (unsigned)((jc & 1) * 16 + st * 4 + quad);
#pragma unroll
          for (int reg = 0; reg < 4; ++reg) {
            float e = exp8(scv[st][rg][reg]);
            pv[reg] = ((wd4[reg] >> shb) & 1u) ? 0.f : e;
          }
          pfa[st][rg] = pack4(pv);
        }
      }
    }
    // PV: outa[rg][dsub] += P^T_frag (A) x Y (B from YTS, b64 reads);
    // outs[rg] += P^T_frag x ones -> row sums on the MFMA pipe
    __builtin_amdgcn_s_setprio(1);
#pragma unroll
    for (int st = 0; st < 4; ++st) {
#pragma unroll
      for (int dsub = 0; dsub < 4; ++dsub) {
        uint2 q = *reinterpret_cast<const uint2*>(&YTS[buf][(dsub * 16 + lane15) * 72 + st * 16 + quad * 4]);
        f16x4 yb = __builtin_bit_cast(f16x4, q);
#pragma unroll
        for (int rg = 0; rg < 2; ++rg)
          outa[rg][dsub] = __builtin_amdgcn_mfma_f32_16x16x16f16(pfa[st][rg], yb, outa[rg][dsub], 0, 0, 0);
      }
#pragma unroll
      for (int rg = 0; rg < 2; ++rg)
        outs[rg] = __builtin_amdgcn_mfma_f32_16x16x16f16(pfa[st][rg], onesf, outs[rg], 0, 0, 0);
    }
    __builtin_amdgcn_s_setprio(0);
  }

  // row sums came out of the ones-MFMA: C(row=quad*4+reg, col=*) all-equal per row
  float rinv[2][4];
#pragma unroll
  for (int rg = 0; rg < 2; ++rg)
#pragma unroll
    for (int reg = 0; reg < 4; ++reg)
      rinv[rg][reg] = 1.0f / outs[rg][reg];

  int b = bh / NH, h = bh % NH;
#pragma unroll
  for (int rg = 0; rg < 2; ++rg)
#pragma unroll
    for (int dsub = 0; dsub < 4; ++dsub)
#pragma unroll
      for (int reg = 0; reg < 4; ++reg) {
        float v = outa[rg][dsub][reg] * rinv[rg][reg];
        int srow = s0w + rg * 16 + quad * 4 + reg;
        size_t idxo = ((size_t)(b * S) + srow) * DMODEL + h * DK + dsub * 16 + lane15;
        outc[idxo] = f2bf(v);
      }
}

// ---------------- LayerNorm over 768 (f16 input), ONE WAVE per row ----------------
// Vectorized: ushort4 loads (8B/lane), float4 stores (16B/lane), wave-only shfl reduce.
__global__ __launch_bounds__(256) void k_ln(const unsigned short* __restrict__ f1,
                                            const unsigned short* __restrict__ f2,
                                            const float* __restrict__ g1, const float* __restrict__ b1,
                                            const float* __restrict__ g2, const float* __restrict__ b2,
                                            float* __restrict__ out) {
  int tid = threadIdx.x;
  int w = tid >> 6, lane = tid & 63;
  int rowg = blockIdx.x * 4 + w;        // 0..8191
  int sel = rowg >> 12;
  int row = rowg & 4095;
  const unsigned short* p = (sel ? f2 : f1) + (size_t)row * DMODEL;
  const float* g = sel ? g2 : g1;
  const float* be = sel ? b2 : b1;

  float x[12];
#pragma unroll
  for (int k = 0; k < 3; ++k) {
    ushort4 v = *reinterpret_cast<const ushort4*>(p + k * 256 + lane * 4);
    x[k * 4 + 0] = (float)__builtin_bit_cast(_Float16, v.x);
    x[k * 4 + 1] = (float)__builtin_bit_cast(_Float16, v.y);
    x[k * 4 + 2] = (float)__builtin_bit_cast(_Float16, v.z);
    x[k * 4 + 3] = (float)__builtin_bit_cast(_Float16, v.w);
  }
  float s = 0.f, ss = 0.f;
#pragma unroll
  for (int i = 0; i < 12; ++i) { s += x[i]; ss += x[i] * x[i]; }
#pragma unroll
  for (int m = 1; m < 64; m <<= 1) { s += __shfl_xor(s, m); ss += __shfl_xor(ss, m); }
  float mu = s * (1.0f / 768.0f);
  float var = ss * (1.0f / 768.0f) - mu * mu;
  float rstd = rsqrtf(var + 1e-5f);

  float* o = out + ((size_t)sel * M4 + row) * DMODEL;
#pragma unroll
  for (int k = 0; k < 3; ++k) {
    float4 gv = *reinterpret_cast<const float4*>(g + k * 256 + lane * 4);
    float4 bv = *reinterpret_cast<const float4*>(be + k * 256 + lane * 4);
    float4 ov;
    ov.x = (x[k * 4 + 0] - mu) * rstd * gv.x + bv.x;
    ov.y = (x[k * 4 + 1] - mu) * rstd * gv.y + bv.y;
    ov.z = (x[k * 4 + 2] - mu) * rstd * gv.z + bv.z;
    ov.w = (x[k * 4 + 3] - mu) * rstd * gv.w + bv.w;
    *reinterpret_cast<float4*>(o + k * 256 + lane * 4) = ov;
  }
}

extern "C" void kernel_launch(void* const* d_in, const int* in_sizes, int n_in,
                              void* d_out, int out_size, void* d_ws, size_t ws_size,
                              hipStream_t stream) {
  const float* pro1 = (const float*)d_in[0];
  const float* pro2 = (const float*)d_in[1];
  const int* mask = (const int*)d_in[2];
  const float* WQ = (const float*)d_in[3];
  const float* WK = (const float*)d_in[4];
  const float* FC1 = (const float*)d_in[5];
  const float* g1 = (const float*)d_in[6];
  const float* b1 = (const float*)d_in[7];
  const float* g2 = (const float*)d_in[8];
  const float* b2 = (const float*)d_in[9];
  float* out = (float*)d_out;
  char* ws = (char*)d_ws;

  // workspace layout (bytes)
  unsigned short* f1h = (unsigned short*)(ws + 0);            // 6291456 f16 (pre-LN path1)
  unsigned short* wqt = (unsigned short*)(ws + 12582912);     // 1179648
  unsigned short* wkt = (unsigned short*)(ws + 13762560);     // 1179648
  unsigned short* fc1t = (unsigned short*)(ws + 14942208);    // 1179648
  unsigned short* Qb = (unsigned short*)(ws + 16121856);      // 6291456 f16 [bh][s][d]
  unsigned short* Kb = (unsigned short*)(ws + 22413312);      // 6291456 f16
  unsigned short* QT = (unsigned short*)(ws + 28704768);      // 6291456 f16 [bh][d][s]
  unsigned short* KT = (unsigned short*)(ws + 34996224);      // 6291456 f16
  unsigned int* mp2 = (unsigned int*)(ws + 41287680);         // 6291456
  unsigned short* f2h = (unsigned short*)(ws + 47579136);     // 6291456 f16
  unsigned short* c1 = (unsigned short*)(ws + 60162048);      // 6291456 bf16
  unsigned short* c2 = (unsigned short*)(ws + 66453504);      // 6291456 bf16

  k_prep<<<1728, 256, 0, stream>>>(WQ, WK, FC1, wqt, wkt, fc1t);
  k_g0p<<<1536, 256, 0, stream>>>(pro1, pro2, wqt, wkt, Qb, Kb, QT, KT, mask, mp2);
  k_attn<<<dim3(768), 256, 0, stream>>>(Qb, Kb, QT, KT, mp2, c1, c2);
  k_gemm1<<<768, 256, 0, stream>>>(c1, c2, fc1t, f1h, f2h);
  k_ln<<<2048, 256, 0, stream>>>(f1h, f2h, g1, b1, g2, b2, out);
}